// Round 24
// baseline (222.094 us; speedup 1.0000x reference)
//
#include <hip/hip_runtime.h>

// R24: production = R23 (best, 53.3us). DIAGNOSTIC shadows: two amplified
// scatter ablations into scratch isolate which component eats scatter's
// 20.6us (invariant so far to occupancy, write pattern, staging, pipelining):
//   V_noTV  = R23 scatter minus 3 tv ds_add_f32 atomics
//   V_noRec = R23 scatter minus {scan, pass2, sweep} (pass1 kept live via asm)
// Readout: dur/8 per variant vs 20.6 full. R25 ships the indicated fix.

#define NMOL   32
#define NATOM  512
#define NPAIR  32768
#define NB     64
#define HIDDEN 256
#define TOTNATOM (NMOL * NATOM)
#define NSUB   8
#define BLKCAP 2560
#define ABLK   8
#define SLOTS  128
#define SREP   8

typedef __attribute__((ext_vector_type(8))) short bf16x8;
typedef __attribute__((ext_vector_type(4))) float f32x4;

__device__ __forceinline__ unsigned short f2bf(float x) {   // RNE f32->bf16
    unsigned u = __float_as_uint(x);
    u += 0x7FFFu + ((u >> 16) & 1u);
    return (unsigned short)(u >> 16);
}

// ---------------------------------------------------------------------------
// K1 scatter (production, verbatim R23)
// ---------------------------------------------------------------------------
__global__ __launch_bounds__(1024) void scatter_kernel(
    const float* __restrict__ cart, const float* __restrict__ shifts,
    const int* __restrict__ species, const int* __restrict__ atom_index,
    unsigned* __restrict__ cnt, unsigned* __restrict__ soff_g,
    float2* __restrict__ rec, float* __restrict__ tv_part,
    float* __restrict__ dipole, int ndip)
{
    __shared__ float    tv_sc[NATOM * 3];
    __shared__ float    s_cart[NATOM * 3];
    __shared__ int      s_sp[NATOM];
    __shared__ unsigned lcnt[NATOM];
    __shared__ unsigned pref[NATOM];
    __shared__ unsigned pcnt[NATOM];
    __shared__ unsigned stot;
    __shared__ float2   list[BLKCAP];

    const int tid  = threadIdx.x;
    const int lane = tid & 63;
    const int wave = tid >> 6;
    const int b    = blockIdx.x;
    const int mol  = b >> 3;
    const int sub  = b & 7;

    if (b == 0 && tid < ndip) dipole[tid] = 0.f;

    const float* cm = cart + (size_t)mol * NATOM * 3;
    const int*   sp = species + (size_t)mol * NATOM;
    for (int i = tid; i < NATOM * 3; i += 1024) { tv_sc[i] = 0.f; s_cart[i] = cm[i]; }
    if (tid < NATOM) { lcnt[tid] = 0u; pcnt[tid] = 0u; s_sp[tid] = sp[tid]; }
    __syncthreads();

    const int* ai0 = atom_index + (size_t)mol * NPAIR;
    const int* ai1 = ai0 + (size_t)NMOL * NPAIR;
    const float* sh = shifts + (size_t)mol * NPAIR * 3;
    const int base = sub * 4096;

    int   gi0[4], gi1[4];
    float gsx[4], gsy[4], gsz[4];
#pragma unroll
    for (int k = 0; k < 4; ++k) {
        const int p = base + k * 1024 + tid;
        gi0[k] = ai0[p];
        gi1[k] = ai1[p];
        gsx[k] = sh[p * 3 + 0];
        gsy[k] = sh[p * 3 + 1];
        gsz[k] = sh[p * 3 + 2];
    }

    float    rd[4];
    unsigned rf[4];
    int      ri[4];
#pragma unroll
    for (int k = 0; k < 4; ++k) {
        const int a3 = gi0[k] * 3, b3 = gi1[k] * 3;
        const float m = (gsx[k] > -1e10f && gsy[k] > -1e10f && gsz[k] > -1e10f)
                        ? 1.f : 0.f;
        const float dx = (s_cart[a3 + 0] - s_cart[b3 + 0] + gsx[k]) * m;
        const float dy = (s_cart[a3 + 1] - s_cart[b3 + 1] + gsy[k]) * m;
        const float dz = (s_cart[a3 + 2] - s_cart[b3 + 2] + gsz[k]) * m;
        unsafeAtomicAdd(&tv_sc[a3 + 0], dx);
        unsafeAtomicAdd(&tv_sc[a3 + 1], dy);
        unsafeAtomicAdd(&tv_sc[a3 + 2], dz);
        const float d = sqrtf(dx * dx + dy * dy + dz * dz + 1e-12f);
        ri[k] = -1;
        if (d < 5.0f && m != 0.f) {
            const float fc = 0.5f * (__cosf(0.62831853071795864769f * d) + 1.f);
            rd[k] = d;
            rf[k] = (__float_as_uint(fc) & ~7u) | (unsigned)s_sp[gi1[k]];
            ri[k] = gi0[k];
            atomicAdd(&lcnt[gi0[k]], 1u);
        }
    }
    __syncthreads();

    if (wave == 0) {
        unsigned c[8], s = 0;
#pragma unroll
        for (int j = 0; j < 8; ++j) { c[j] = lcnt[lane * 8 + j]; s += c[j]; }
        unsigned incl = s;
#pragma unroll
        for (int off = 1; off < 64; off <<= 1) {
            const unsigned v = __shfl_up(incl, off);
            if (lane >= off) incl += v;
        }
        unsigned run = incl - s;
#pragma unroll
        for (int j = 0; j < 8; ++j) { pref[lane * 8 + j] = run; run += c[j]; }
        if (lane == 63) stot = incl;
    }
    __syncthreads();

#pragma unroll
    for (int k = 0; k < 4; ++k) {
        if (ri[k] >= 0) {
            const unsigned pos = atomicAdd(&pcnt[ri[k]], 1u);
            const unsigned idx = pref[ri[k]] + pos;
            if (idx < (unsigned)BLKCAP)
                list[idx] = make_float2(rd[k], __uint_as_float(rf[k]));
        }
    }
    __syncthreads();

    const int tot = min((int)stot, BLKCAP);
    float2* dstr = rec + (size_t)b * BLKCAP;
    for (int i = tid; i < tot; i += 1024) dstr[i] = list[i];

    if (tid < NATOM) {
        cnt[((size_t)mol * NATOM + tid) * NSUB + sub] = lcnt[tid];
        soff_g[(size_t)b * NATOM + tid] = pref[tid];
    }
    float* tg = tv_part + (size_t)b * NATOM * 3;
    for (int i = tid; i < NATOM * 3; i += 1024) tg[i] = tv_sc[i];
}

// ---------------------------------------------------------------------------
// SHADOW V_noTV: R23 scatter minus the 3 tv ds_add_f32 (amplified, scratch).
// ---------------------------------------------------------------------------
__global__ __launch_bounds__(1024) void scat_noTV_kernel(
    const float* __restrict__ cart, const float* __restrict__ shifts,
    const int* __restrict__ species, const int* __restrict__ atom_index,
    unsigned* __restrict__ cnt, unsigned* __restrict__ soff_g,
    float2* __restrict__ rec, float* __restrict__ tv_part, int reps)
{
    __shared__ float    tv_sc[NATOM * 3];
    __shared__ float    s_cart[NATOM * 3];
    __shared__ int      s_sp[NATOM];
    __shared__ unsigned lcnt[NATOM];
    __shared__ unsigned pref[NATOM];
    __shared__ unsigned pcnt[NATOM];
    __shared__ unsigned stot;
    __shared__ float2   list[BLKCAP];

    const int tid  = threadIdx.x;
    const int lane = tid & 63;
    const int wave = tid >> 6;
    const int b    = blockIdx.x;
    const int mol  = b >> 3;
    const int sub  = b & 7;

    const float* cm = cart + (size_t)mol * NATOM * 3;
    const int*   sp = species + (size_t)mol * NATOM;
    for (int i = tid; i < NATOM * 3; i += 1024) { tv_sc[i] = 0.f; s_cart[i] = cm[i]; }
    if (tid < NATOM) s_sp[tid] = sp[tid];

    const int* ai0 = atom_index + (size_t)mol * NPAIR;
    const int* ai1 = ai0 + (size_t)NMOL * NPAIR;
    const float* sh = shifts + (size_t)mol * NPAIR * 3;
    const int base = sub * 4096;

    for (int rep = 0; rep < reps; ++rep) {
        __syncthreads();
        if (tid < NATOM) { lcnt[tid] = 0u; pcnt[tid] = 0u; }
        __syncthreads();

        int   gi0[4], gi1[4];
        float gsx[4], gsy[4], gsz[4];
#pragma unroll
        for (int k = 0; k < 4; ++k) {
            const int p = base + k * 1024 + tid;
            gi0[k] = ai0[p];
            gi1[k] = ai1[p];
            gsx[k] = sh[p * 3 + 0];
            gsy[k] = sh[p * 3 + 1];
            gsz[k] = sh[p * 3 + 2];
        }

        float    rd[4];
        unsigned rf[4];
        int      ri[4];
#pragma unroll
        for (int k = 0; k < 4; ++k) {
            const int a3 = gi0[k] * 3, b3 = gi1[k] * 3;
            const float m = (gsx[k] > -1e10f && gsy[k] > -1e10f && gsz[k] > -1e10f)
                            ? 1.f : 0.f;
            const float dx = (s_cart[a3 + 0] - s_cart[b3 + 0] + gsx[k]) * m;
            const float dy = (s_cart[a3 + 1] - s_cart[b3 + 1] + gsy[k]) * m;
            const float dz = (s_cart[a3 + 2] - s_cart[b3 + 2] + gsz[k]) * m;
            // (tv atomics DELETED -- the ablation)
            const float d = sqrtf(dx * dx + dy * dy + dz * dz + 1e-12f);
            ri[k] = -1;
            if (d < 5.0f && m != 0.f) {
                const float fc = 0.5f * (__cosf(0.62831853071795864769f * d) + 1.f);
                rd[k] = d;
                rf[k] = (__float_as_uint(fc) & ~7u) | (unsigned)s_sp[gi1[k]];
                ri[k] = gi0[k];
                atomicAdd(&lcnt[gi0[k]], 1u);
            }
        }
        __syncthreads();

        if (wave == 0) {
            unsigned c[8], s = 0;
#pragma unroll
            for (int j = 0; j < 8; ++j) { c[j] = lcnt[lane * 8 + j]; s += c[j]; }
            unsigned incl = s;
#pragma unroll
            for (int off = 1; off < 64; off <<= 1) {
                const unsigned v = __shfl_up(incl, off);
                if (lane >= off) incl += v;
            }
            unsigned run = incl - s;
#pragma unroll
            for (int j = 0; j < 8; ++j) { pref[lane * 8 + j] = run; run += c[j]; }
            if (lane == 63) stot = incl;
        }
        __syncthreads();

#pragma unroll
        for (int k = 0; k < 4; ++k) {
            if (ri[k] >= 0) {
                const unsigned pos = atomicAdd(&pcnt[ri[k]], 1u);
                const unsigned idx = pref[ri[k]] + pos;
                if (idx < (unsigned)BLKCAP)
                    list[idx] = make_float2(rd[k], __uint_as_float(rf[k]));
            }
        }
        __syncthreads();

        const int tot = min((int)stot, BLKCAP);
        float2* dstr = rec + (size_t)b * BLKCAP;
        for (int i = tid; i < tot; i += 1024) dstr[i] = list[i];
        if (tid < NATOM) {
            cnt[((size_t)mol * NATOM + tid) * NSUB + sub] = lcnt[tid];
            soff_g[(size_t)b * NATOM + tid] = pref[tid];
        }
        float* tg = tv_part + (size_t)b * NATOM * 3;
        for (int i = tid; i < NATOM * 3; i += 1024) tg[i] = tv_sc[i];
    }
}

// ---------------------------------------------------------------------------
// SHADOW V_noRec: R23 scatter minus {scan, pass2, sweep}; pass 1 complete,
// rd/rf kept live via asm (rule: ablation-via-skip DCEs upstream ops).
// ---------------------------------------------------------------------------
__global__ __launch_bounds__(1024) void scat_noRec_kernel(
    const float* __restrict__ cart, const float* __restrict__ shifts,
    const int* __restrict__ species, const int* __restrict__ atom_index,
    unsigned* __restrict__ cnt, unsigned* __restrict__ soff_g,
    float2* __restrict__ rec, float* __restrict__ tv_part, int reps)
{
    __shared__ float    tv_sc[NATOM * 3];
    __shared__ float    s_cart[NATOM * 3];
    __shared__ int      s_sp[NATOM];
    __shared__ unsigned lcnt[NATOM];

    const int tid = threadIdx.x;
    const int b   = blockIdx.x;
    const int mol = b >> 3;
    const int sub = b & 7;

    const float* cm = cart + (size_t)mol * NATOM * 3;
    const int*   sp = species + (size_t)mol * NATOM;
    for (int i = tid; i < NATOM * 3; i += 1024) s_cart[i] = cm[i];
    if (tid < NATOM) s_sp[tid] = sp[tid];

    const int* ai0 = atom_index + (size_t)mol * NPAIR;
    const int* ai1 = ai0 + (size_t)NMOL * NPAIR;
    const float* sh = shifts + (size_t)mol * NPAIR * 3;
    const int base = sub * 4096;

    for (int rep = 0; rep < reps; ++rep) {
        __syncthreads();
        for (int i = tid; i < NATOM * 3; i += 1024) tv_sc[i] = 0.f;
        if (tid < NATOM) lcnt[tid] = 0u;
        __syncthreads();

        int   gi0[4], gi1[4];
        float gsx[4], gsy[4], gsz[4];
#pragma unroll
        for (int k = 0; k < 4; ++k) {
            const int p = base + k * 1024 + tid;
            gi0[k] = ai0[p];
            gi1[k] = ai1[p];
            gsx[k] = sh[p * 3 + 0];
            gsy[k] = sh[p * 3 + 1];
            gsz[k] = sh[p * 3 + 2];
        }

#pragma unroll
        for (int k = 0; k < 4; ++k) {
            const int a3 = gi0[k] * 3, b3 = gi1[k] * 3;
            const float m = (gsx[k] > -1e10f && gsy[k] > -1e10f && gsz[k] > -1e10f)
                            ? 1.f : 0.f;
            const float dx = (s_cart[a3 + 0] - s_cart[b3 + 0] + gsx[k]) * m;
            const float dy = (s_cart[a3 + 1] - s_cart[b3 + 1] + gsy[k]) * m;
            const float dz = (s_cart[a3 + 2] - s_cart[b3 + 2] + gsz[k]) * m;
            unsafeAtomicAdd(&tv_sc[a3 + 0], dx);
            unsafeAtomicAdd(&tv_sc[a3 + 1], dy);
            unsafeAtomicAdd(&tv_sc[a3 + 2], dz);
            const float d = sqrtf(dx * dx + dy * dy + dz * dz + 1e-12f);
            if (d < 5.0f && m != 0.f) {
                const float fc = 0.5f * (__cosf(0.62831853071795864769f * d) + 1.f);
                const float    rdk = d;
                const unsigned rfk = (__float_as_uint(fc) & ~7u) | (unsigned)s_sp[gi1[k]];
                asm volatile("" :: "v"(rdk), "v"(rfk));   // keep fc/cos live
                atomicAdd(&lcnt[gi0[k]], 1u);
            }
        }
        __syncthreads();
        // (scan, pass2, sweep DELETED -- the ablation)

        if (tid < NATOM) {
            cnt[((size_t)mol * NATOM + tid) * NSUB + sub] = lcnt[tid];
            soff_g[(size_t)b * NATOM + tid] = lcnt[tid];   // placeholder traffic
        }
        float* tg = tv_part + (size_t)b * NATOM * 3;
        for (int i = tid; i < NATOM * 3; i += 1024) tg[i] = tv_sc[i];
    }
}

// ---------------------------------------------------------------------------
// K2 gather: verbatim R23.
// ---------------------------------------------------------------------------
__global__ __launch_bounds__(256) void gather_kernel(
    const unsigned* __restrict__ cnt, const unsigned* __restrict__ soff_g,
    const float2* __restrict__ rec,
    const float* __restrict__ centers, const float* __restrict__ widths,
    const float* __restrict__ c_emb, const float* __restrict__ tv_part,
    unsigned short* __restrict__ dens_bf, float* __restrict__ tvv)
{
    __shared__ float    cemb[8 * NB];
    __shared__ float2   list[ABLK][SLOTS];
    __shared__ unsigned scnt[ABLK][NSUB];
    __shared__ unsigned sofg[ABLK][NSUB];
    __shared__ unsigned soff[ABLK][NSUB];
    __shared__ unsigned mtot[ABLK];

    const int tid = threadIdx.x;
    const int a0  = blockIdx.x * ABLK;
    const int mol = a0 >> 9;
    const int ra0 = a0 & 511;

    for (int i = tid; i < 8 * NB; i += 256) cemb[i] = c_emb[i];
    if (tid < ABLK * NSUB) {
        const int al = tid >> 3, s = tid & 7;
        scnt[al][s] = cnt[(size_t)(a0 + al) * NSUB + s];
        sofg[al][s] = soff_g[(size_t)(mol * NSUB + s) * NATOM + (ra0 + al)];
    }
    __syncthreads();

    if (tid < ABLK) {
        int o = 0;
#pragma unroll
        for (int s = 0; s < NSUB; ++s) {
            soff[tid][s] = (unsigned)o;
            o += min((int)scnt[tid][s], SLOTS - o);
        }
        const int mp = (o + 7) & ~7;
        mtot[tid] = (unsigned)mp;
        for (int k = o; k < mp; ++k) list[tid][k] = make_float2(0.f, 0.f);
    }
    __syncthreads();

    {
        const int seg = tid >> 2;
        const int prt = tid & 3;
        const int al = seg >> 3, s = seg & 7;
        const int off = (int)soff[al][s];
        const int n = min((int)scnt[al][s], SLOTS - off);
        const float2* src = rec + (size_t)(mol * NSUB + s) * BLKCAP + sofg[al][s];
        float2* dst = &list[al][off];
        const int k0 = prt * 5, k1 = min(k0 + 5, n);
        for (int k = k0; k < k1; ++k) dst[k] = src[k];
    }
    if (tid < ABLK * 3) {
        const int al = tid / 3, c = tid - al * 3;
        float s = 0.f;
#pragma unroll
        for (int sb = 0; sb < NSUB; ++sb)
            s += tv_part[((size_t)(mol * NSUB + sb) * NATOM + (ra0 + al)) * 3 + c];
        tvv[(size_t)(a0 + al) * 3 + c] = s;
    }
    __syncthreads();

    const int lane = tid & 63;
    const int wave = tid >> 6;
    const float L2E = 1.4426950408889634f;
    const float wl  = widths[lane];
    const float cl  = centers[lane];
    const float e2  = -wl * L2E;
    const float b2  = 2.f * wl * cl * L2E;
    const float a2  = -wl * cl * cl * L2E;

#define REC1(A, dv, fv) { const unsigned f_ = __float_as_uint(fv);           \
        const float v_ = fmaf(dv, fmaf(dv, e2, b2), a2);                     \
        A = fmaf(exp2f(v_) * __uint_as_float(f_ & ~7u),                      \
                 cemb[((f_ & 7u) << 6) | lane], A); }

    for (int al = wave; al < ABLK; al += 4) {
        const int m = (int)mtot[al];
        const float4* l4 = reinterpret_cast<const float4*>(list[al]);
        float acc0 = 0.f, acc1 = 0.f;
        for (int j = 0; j < m; j += 8) {
            const float4 q0 = l4[(j >> 1) + 0];
            const float4 q1 = l4[(j >> 1) + 1];
            const float4 q2 = l4[(j >> 1) + 2];
            const float4 q3 = l4[(j >> 1) + 3];
            REC1(acc0, q0.x, q0.y) REC1(acc1, q0.z, q0.w)
            REC1(acc0, q1.x, q1.y) REC1(acc1, q1.z, q1.w)
            REC1(acc0, q2.x, q2.y) REC1(acc1, q2.z, q2.w)
            REC1(acc0, q3.x, q3.y) REC1(acc1, q3.z, q3.w)
        }
        dens_bf[(size_t)(a0 + al) * NB + lane] = f2bf(acc0 + acc1);
    }
#undef REC1
}

// ---------------------------------------------------------------------------
// K3 nn via MFMA: verbatim R23.
// ---------------------------------------------------------------------------
__global__ __launch_bounds__(256) void nn_kernel(
    const unsigned short* __restrict__ dens_bf, const float* __restrict__ tvv,
    const float* __restrict__ W1, const float* __restrict__ b1,
    const float* __restrict__ W2, const float* __restrict__ b2,
    float* __restrict__ dipole)
{
    __shared__ __align__(16) unsigned short w1t[HIDDEN * 72];
    __shared__ float b1_l[HIDDEN], w2_l[HIDDEN];
    __shared__ float sred[4][4][3];

    const int tid = threadIdx.x;
    const int mol = blockIdx.x >> 3;

    for (int i = tid; i < NB * HIDDEN; i += 256) {
        const int k = i >> 8, j = i & 255;
        w1t[j * 72 + k] = f2bf(W1[i]);
    }
    if (tid < HIDDEN) { b1_l[tid] = b1[tid]; w2_l[tid] = W2[tid]; }
    __syncthreads();

    const int lane = tid & 63;
    const int wave = tid >> 6;
    const int fr   = lane & 15;
    const int fg   = lane >> 4;
    const int a0w  = blockIdx.x * 64 + wave * 16;

    bf16x8 afr[2];
#pragma unroll
    for (int kk = 0; kk < 2; ++kk)
        afr[kk] = *reinterpret_cast<const bf16x8*>(
            dens_bf + (size_t)(a0w + fr) * NB + kk * 32 + fg * 8);

    float sdip[4] = {0.f, 0.f, 0.f, 0.f};
#pragma unroll
    for (int nt = 0; nt < 16; ++nt) {
        const bf16x8 bf0 = *reinterpret_cast<const bf16x8*>(
            &w1t[(nt * 16 + fr) * 72 + 0 + fg * 8]);
        const bf16x8 bf1 = *reinterpret_cast<const bf16x8*>(
            &w1t[(nt * 16 + fr) * 72 + 32 + fg * 8]);
        f32x4 acc = {0.f, 0.f, 0.f, 0.f};
        acc = __builtin_amdgcn_mfma_f32_16x16x32_bf16(afr[0], bf0, acc, 0, 0, 0);
        acc = __builtin_amdgcn_mfma_f32_16x16x32_bf16(afr[1], bf1, acc, 0, 0, 0);
        const int j = nt * 16 + fr;
        const float b1v = b1_l[j], w2v = w2_l[j];
#pragma unroll
        for (int i = 0; i < 4; ++i) {
            const float h = acc[i] + b1v;
            sdip[i] += (h / (1.f + __expf(-h))) * w2v;
        }
    }
#pragma unroll
    for (int off = 1; off < 16; off <<= 1) {
#pragma unroll
        for (int i = 0; i < 4; ++i) sdip[i] += __shfl_xor(sdip[i], off);
    }
    if (fr == 0) {
        const float b2v = b2[0];
        float px = 0.f, py = 0.f, pz = 0.f;
#pragma unroll
        for (int i = 0; i < 4; ++i) {
            const int a = a0w + fg * 4 + i;
            const float out = sdip[i] + b2v;
            px += out * tvv[a * 3 + 0];
            py += out * tvv[a * 3 + 1];
            pz += out * tvv[a * 3 + 2];
        }
        sred[wave][fg][0] = px; sred[wave][fg][1] = py; sred[wave][fg][2] = pz;
    }
    __syncthreads();
    if (tid < 3) {
        float s = 0.f;
#pragma unroll
        for (int w = 0; w < 4; ++w)
#pragma unroll
            for (int g = 0; g < 4; ++g) s += sred[w][g][tid];
        unsafeAtomicAdd(&dipole[mol * 3 + tid], s);
    }
}

// ---------------------------------------------------------------------------
extern "C" void kernel_launch(void* const* d_in, const int* in_sizes, int n_in,
                              void* d_out, int out_size, void* d_ws, size_t ws_size,
                              hipStream_t stream)
{
    const float* cart       = (const float*)d_in[0];
    const float* shifts     = (const float*)d_in[1];
    const float* centers    = (const float*)d_in[2];
    const float* widths     = (const float*)d_in[3];
    const float* c_emb      = (const float*)d_in[4];
    const float* W1         = (const float*)d_in[5];
    const float* b1         = (const float*)d_in[6];
    const float* W2         = (const float*)d_in[7];
    const float* b2         = (const float*)d_in[8];
    const int*   species    = (const int*)d_in[10];
    const int*   atom_index = (const int*)d_in[11];

    // production ws
    float*          tv_part = (float*)d_ws;
    unsigned*       cnt     = (unsigned*)(tv_part + (size_t)NMOL * NSUB * NATOM * 3);
    unsigned*       soff_g  = cnt + (size_t)TOTNATOM * NSUB;
    float*          tvv     = (float*)(soff_g + (size_t)NMOL * NSUB * NATOM);
    unsigned short* dens_bf = (unsigned short*)(tvv + (size_t)TOTNATOM * 3);
    float2*         rec     = (float2*)(dens_bf + (size_t)TOTNATOM * NB);
    // shadow scratch (disjoint, after production rec)
    float*          tv2     = (float*)(rec + (size_t)NMOL * NSUB * BLKCAP);
    unsigned*       cnt2    = (unsigned*)(tv2 + (size_t)NMOL * NSUB * NATOM * 3);
    unsigned*       soff2   = cnt2 + (size_t)TOTNATOM * NSUB;
    float2*         rec2    = (float2*)(soff2 + (size_t)NMOL * NSUB * NATOM);
    float*          dipole  = (float*)d_out;

    hipLaunchKernelGGL(scatter_kernel, dim3(NMOL * NSUB), dim3(1024), 0, stream,
                       cart, shifts, species, atom_index, cnt, soff_g, rec,
                       tv_part, dipole, out_size);
    hipLaunchKernelGGL(gather_kernel, dim3(TOTNATOM / ABLK), dim3(256), 0, stream,
                       cnt, soff_g, rec, centers, widths, c_emb, tv_part,
                       dens_bf, tvv);
    hipLaunchKernelGGL(nn_kernel, dim3(TOTNATOM / 64), dim3(256), 0, stream,
                       dens_bf, tvv, W1, b1, W2, b2, dipole);
    // diagnostic shadows (scratch only, after the real pipeline)
    hipLaunchKernelGGL(scat_noTV_kernel, dim3(NMOL * NSUB), dim3(1024), 0, stream,
                       cart, shifts, species, atom_index, cnt2, soff2, rec2,
                       tv2, SREP);
    hipLaunchKernelGGL(scat_noRec_kernel, dim3(NMOL * NSUB), dim3(1024), 0, stream,
                       cart, shifts, species, atom_index, cnt2, soff2, rec2,
                       tv2, SREP);
}

// Round 25
// 161.394 us; speedup vs baseline: 1.3761x; 1.3761x over previous
//
#include <hip/hip_runtime.h>
#include <hip/hip_cooperative_groups.h>

#define NMOL   32
#define NATOM  512
#define NPAIR  32768
#define NB     64
#define HIDDEN 256
#define TOTNATOM (NMOL * NATOM)
#define NSUB   8
#define BLKCAP 2560
#define SLOT2  64     // per-atom record slots in gather phase (lambda 17, +11 sigma)

typedef __attribute__((ext_vector_type(8))) short bf16x8;
typedef __attribute__((ext_vector_type(4))) float f32x4;

__device__ __forceinline__ unsigned short f2bf(float x) {   // RNE f32->bf16
    unsigned u = __float_as_uint(x);
    u += 0x7FFFu + ((u >> 16) & 1u);
    return (unsigned short)(u >> 16);
}

// ---------------------------------------------------------------------------
// R25: ONE cooperative kernel (256 blocks x 1024 thr, 1/CU).
//   phase 1 = R23 scatter (block = (mol, sub)); threadfence + grid.sync
//   phase 2 = R21 gather for the block's OWN 64 atoms (same mol); density/tv
//             stay in LDS (dens_bf/tvv global round-trips deleted)
//   phase 3 = R21 MFMA nn from LDS; 3 dipole atomics/block
// Rationale: R20/R24 accounting shows kernels sum to ~36 of 53.3us; the
// ~17us X lives BETWEEN dispatches (gaps/tails/cold-cache). One dispatch
// removes all boundaries. Phase code verbatim from proven kernels; LDS
// regions manually unioned (peak 53KB); no per-thread arrays > 20 regs.
// ---------------------------------------------------------------------------
__global__ __launch_bounds__(1024) void fused_kernel(
    const float* __restrict__ cart, const float* __restrict__ shifts,
    const float* __restrict__ centers, const float* __restrict__ widths,
    const float* __restrict__ c_emb, const int* __restrict__ species,
    const int* __restrict__ atom_index,
    const float* __restrict__ W1, const float* __restrict__ b1,
    const float* __restrict__ W2, const float* __restrict__ b2,
    unsigned* __restrict__ cnt, unsigned* __restrict__ soff_g,
    float2* __restrict__ rec, float* __restrict__ tv_part,
    float* __restrict__ dipole, int ndip)
{
    // ---- unioned LDS: dens_l(9216) | tv_l(768) | cemb(2048) | big(40960) ----
    __shared__ __align__(16) char smem[52992];
    __shared__ unsigned stot;
    unsigned short (*dens_l)[72] = reinterpret_cast<unsigned short(*)[72]>(smem);
    float* tv_l = reinterpret_cast<float*>(smem + 9216);
    float* cemb = reinterpret_cast<float*>(smem + 9984);
    char*  big  = smem + 12032;

    const int tid  = threadIdx.x;
    const int lane = tid & 63;
    const int wave = tid >> 6;
    const int b    = blockIdx.x;
    const int mol  = b >> 3;
    const int sub  = b & 7;

    // ================= phase 1: scatter (verbatim R23) =================
    {
        float*    s_cart = reinterpret_cast<float*>(big);
        float*    tv_sc  = reinterpret_cast<float*>(big + 6144);
        int*      s_sp   = reinterpret_cast<int*>(big + 12288);
        unsigned* lcnt   = reinterpret_cast<unsigned*>(big + 14336);
        unsigned* pref   = reinterpret_cast<unsigned*>(big + 16384);
        unsigned* pcnt   = reinterpret_cast<unsigned*>(big + 18432);
        float2*   list   = reinterpret_cast<float2*>(big + 20480);

        if (b == 0 && tid < ndip) dipole[tid] = 0.f;

        const float* cm = cart + (size_t)mol * NATOM * 3;
        const int*   sp = species + (size_t)mol * NATOM;
        for (int i = tid; i < NATOM * 3; i += 1024) { tv_sc[i] = 0.f; s_cart[i] = cm[i]; }
        if (tid < NATOM) { lcnt[tid] = 0u; pcnt[tid] = 0u; s_sp[tid] = sp[tid]; }
        __syncthreads();

        const int* ai0 = atom_index + (size_t)mol * NPAIR;
        const int* ai1 = ai0 + (size_t)NMOL * NPAIR;
        const float* sh = shifts + (size_t)mol * NPAIR * 3;
        const int base = sub * 4096;

        int   gi0[4], gi1[4];
        float gsx[4], gsy[4], gsz[4];
#pragma unroll
        for (int k = 0; k < 4; ++k) {
            const int p = base + k * 1024 + tid;
            gi0[k] = ai0[p];
            gi1[k] = ai1[p];
            gsx[k] = sh[p * 3 + 0];
            gsy[k] = sh[p * 3 + 1];
            gsz[k] = sh[p * 3 + 2];
        }

        float    rd[4];
        unsigned rf[4];
        int      ri[4];
#pragma unroll
        for (int k = 0; k < 4; ++k) {
            const int a3 = gi0[k] * 3, b3 = gi1[k] * 3;
            const float m = (gsx[k] > -1e10f && gsy[k] > -1e10f && gsz[k] > -1e10f)
                            ? 1.f : 0.f;
            const float dx = (s_cart[a3 + 0] - s_cart[b3 + 0] + gsx[k]) * m;
            const float dy = (s_cart[a3 + 1] - s_cart[b3 + 1] + gsy[k]) * m;
            const float dz = (s_cart[a3 + 2] - s_cart[b3 + 2] + gsz[k]) * m;
            unsafeAtomicAdd(&tv_sc[a3 + 0], dx);
            unsafeAtomicAdd(&tv_sc[a3 + 1], dy);
            unsafeAtomicAdd(&tv_sc[a3 + 2], dz);
            const float d = sqrtf(dx * dx + dy * dy + dz * dz + 1e-12f);
            ri[k] = -1;
            if (d < 5.0f && m != 0.f) {
                const float fc = 0.5f * (__cosf(0.62831853071795864769f * d) + 1.f);
                rd[k] = d;
                rf[k] = (__float_as_uint(fc) & ~7u) | (unsigned)s_sp[gi1[k]];
                ri[k] = gi0[k];
                atomicAdd(&lcnt[gi0[k]], 1u);
            }
        }
        __syncthreads();

        if (wave == 0) {                       // single-wave exclusive scan
            unsigned c[8], s = 0;
#pragma unroll
            for (int j = 0; j < 8; ++j) { c[j] = lcnt[lane * 8 + j]; s += c[j]; }
            unsigned incl = s;
#pragma unroll
            for (int off = 1; off < 64; off <<= 1) {
                const unsigned v = __shfl_up(incl, off);
                if (lane >= off) incl += v;
            }
            unsigned run = incl - s;
#pragma unroll
            for (int j = 0; j < 8; ++j) { pref[lane * 8 + j] = run; run += c[j]; }
            if (lane == 63) stot = incl;
        }
        __syncthreads();

#pragma unroll
        for (int k = 0; k < 4; ++k) {
            if (ri[k] >= 0) {
                const unsigned pos = atomicAdd(&pcnt[ri[k]], 1u);
                const unsigned idx = pref[ri[k]] + pos;
                if (idx < (unsigned)BLKCAP)
                    list[idx] = make_float2(rd[k], __uint_as_float(rf[k]));
            }
        }
        __syncthreads();

        const int tot = min((int)stot, BLKCAP);
        float2* dstr = rec + (size_t)b * BLKCAP;
        for (int i = tid; i < tot; i += 1024) dstr[i] = list[i];
        if (tid < NATOM) {
            cnt[((size_t)mol * NATOM + tid) * NSUB + sub] = lcnt[tid];
            soff_g[(size_t)b * NATOM + tid] = pref[tid];
        }
        float* tg = tv_part + (size_t)b * NATOM * 3;
        for (int i = tid; i < NATOM * 3; i += 1024) tg[i] = tv_sc[i];
    }

    __threadfence();                                     // release rec/cnt/tv
    cooperative_groups::this_grid().sync();              // cross-XCD barrier

    // ================= phase 2: gather (R21 structure, own 64 atoms) ========
    {
        float2   (*list2)[SLOT2] = reinterpret_cast<float2(*)[SLOT2]>(big);  // 32768
        unsigned* scnt2 = reinterpret_cast<unsigned*>(big + 32768);          // [al*8+s]
        unsigned* sofg2 = reinterpret_cast<unsigned*>(big + 34816);
        unsigned* soff2 = reinterpret_cast<unsigned*>(big + 36864);
        unsigned* mtot2 = reinterpret_cast<unsigned*>(big + 38912);

        const int a0  = b * 64;                // block's own atoms (same mol)
        const int ra0 = a0 & 511;

        if (tid < 8 * NB) cemb[tid] = c_emb[tid];
        if (tid < 512) {
            const int al = tid >> 3, s = tid & 7;
            scnt2[tid] = cnt[(size_t)(a0 + al) * NSUB + s];
            sofg2[tid] = soff_g[(size_t)(mol * NSUB + s) * NATOM + (ra0 + al)];
        }
        __syncthreads();

        if (tid < 64) {                        // per-atom prefix + zero-pad
            int o = 0;
#pragma unroll
            for (int s = 0; s < NSUB; ++s) {
                soff2[tid * 8 + s] = (unsigned)o;
                o += min((int)scnt2[tid * 8 + s], SLOT2 - o);
            }
            const int mp = (o + 7) & ~7;
            mtot2[tid] = (unsigned)mp;
            for (int k = o; k < mp; ++k) list2[tid][k] = make_float2(0.f, 0.f);
        }
        if (tid < 64 * 3) {                    // tv: sum the 8 block-partials
            const int al = tid / 3, c = tid - al * 3;
            float s = 0.f;
#pragma unroll
            for (int sb = 0; sb < NSUB; ++sb)
                s += tv_part[((size_t)(mol * NSUB + sb) * NATOM + (ra0 + al)) * 3 + c];
            tv_l[al * 3 + c] = s;
        }
        __syncthreads();

        {   // parallel segment copy: 2 threads per (atom, sub) segment (512)
            const int seg = tid >> 1;
            const int prt = tid & 1;
            const int al = seg >> 3, s = seg & 7;
            const int off = (int)soff2[al * 8 + s];
            const int n = min((int)scnt2[al * 8 + s], SLOT2 - off);
            const float2* src = rec + (size_t)(mol * NSUB + s) * BLKCAP + sofg2[al * 8 + s];
            float2* dst = &list2[al][off];
            for (int k = prt; k < n; k += 2) dst[k] = src[k];
        }
        __syncthreads();

        const float L2E = 1.4426950408889634f;
        const float wl  = widths[lane];
        const float cl  = centers[lane];
        const float qe  = -wl * L2E;
        const float qb  = 2.f * wl * cl * L2E;
        const float qa  = -wl * cl * cl * L2E;

#define REC1(A, dv, fv) { const unsigned f_ = __float_as_uint(fv);           \
        const float v_ = fmaf(dv, fmaf(dv, qe, qb), qa);                     \
        A = fmaf(exp2f(v_) * __uint_as_float(f_ & ~7u),                      \
                 cemb[((f_ & 7u) << 6) | lane], A); }

        for (int al = wave; al < 64; al += 16) {   // wave handles 4 atoms
            const int m = (int)mtot2[al];
            const float4* l4 = reinterpret_cast<const float4*>(list2[al]);
            float acc0 = 0.f, acc1 = 0.f;
            for (int j = 0; j < m; j += 8) {
                const float4 q0 = l4[(j >> 1) + 0];
                const float4 q1 = l4[(j >> 1) + 1];
                const float4 q2 = l4[(j >> 1) + 2];
                const float4 q3 = l4[(j >> 1) + 3];
                REC1(acc0, q0.x, q0.y) REC1(acc1, q0.z, q0.w)
                REC1(acc0, q1.x, q1.y) REC1(acc1, q1.z, q1.w)
                REC1(acc0, q2.x, q2.y) REC1(acc1, q2.z, q2.w)
                REC1(acc0, q3.x, q3.y) REC1(acc1, q3.z, q3.w)
            }
            dens_l[al][lane] = f2bf(acc0 + acc1);   // padded row 72: 2 lanes/bank
        }
#undef REC1
    }
    __syncthreads();                           // list2 dead after this

    // ================= phase 3: MFMA nn (R21 structure, 16 waves) ===========
    {
        unsigned short (*w1t)[72] = reinterpret_cast<unsigned short(*)[72]>(big); // 36864
        float* b1_l = reinterpret_cast<float*>(big + 36864);
        float* w2_l = reinterpret_cast<float*>(big + 37888);
        float* sred = reinterpret_cast<float*>(big + 38912);   // [mt*4+nq][16]

        for (int i = tid; i < NB * HIDDEN; i += 1024) {        // stage W1^T bf16
            const int k = i >> 8, j = i & 255;
            w1t[j][k] = f2bf(W1[i]);
        }
        if (tid < HIDDEN) { b1_l[tid] = b1[tid]; w2_l[tid] = W2[tid]; }
        __syncthreads();

        const int fr = lane & 15;              // C col (j in tile) / A-B row
        const int fg = lane >> 4;              // k-group; C rows = fg*4+i
        const int mt = wave & 3;               // M-tile (16 atoms)
        const int nq = wave >> 2;              // N-quarter (4 N-tiles)

        bf16x8 afr[2];
#pragma unroll
        for (int kk = 0; kk < 2; ++kk)
            afr[kk] = *reinterpret_cast<const bf16x8*>(
                &dens_l[mt * 16 + fr][kk * 32 + fg * 8]);

        float sdip[4] = {0.f, 0.f, 0.f, 0.f};
#pragma unroll
        for (int t = 0; t < 4; ++t) {
            const int nt = nq * 4 + t;
            const bf16x8 bf0 = *reinterpret_cast<const bf16x8*>(
                &w1t[nt * 16 + fr][0 + fg * 8]);
            const bf16x8 bf1 = *reinterpret_cast<const bf16x8*>(
                &w1t[nt * 16 + fr][32 + fg * 8]);
            f32x4 acc = {0.f, 0.f, 0.f, 0.f};
            acc = __builtin_amdgcn_mfma_f32_16x16x32_bf16(afr[0], bf0, acc, 0, 0, 0);
            acc = __builtin_amdgcn_mfma_f32_16x16x32_bf16(afr[1], bf1, acc, 0, 0, 0);
            const int j = nt * 16 + fr;
            const float b1v = b1_l[j], w2v = w2_l[j];
#pragma unroll
            for (int i = 0; i < 4; ++i) {      // silu * W2, accumulate
                const float h = acc[i] + b1v;
                sdip[i] += (h / (1.f + __expf(-h))) * w2v;
            }
        }
#pragma unroll
        for (int off = 1; off < 16; off <<= 1) {   // reduce over 16 j-cols
#pragma unroll
            for (int i = 0; i < 4; ++i) sdip[i] += __shfl_xor(sdip[i], off);
        }
        if (fr == 0) {
#pragma unroll
            for (int i = 0; i < 4; ++i)
                sred[(mt * 4 + nq) * 16 + fg * 4 + i] = sdip[i];
        }
        __syncthreads();

        if (tid < 64) {                        // atom a = tid (one wave)
            const int a = tid;
            float out = b2[0];
#pragma unroll
            for (int q = 0; q < 4; ++q) out += sred[((a >> 4) * 4 + q) * 16 + (a & 15)];
            float px = out * tv_l[a * 3 + 0];
            float py = out * tv_l[a * 3 + 1];
            float pz = out * tv_l[a * 3 + 2];
#pragma unroll
            for (int off = 32; off; off >>= 1) {
                px += __shfl_down(px, off);
                py += __shfl_down(py, off);
                pz += __shfl_down(pz, off);
            }
            if (a == 0) {
                unsafeAtomicAdd(&dipole[mol * 3 + 0], px);
                unsafeAtomicAdd(&dipole[mol * 3 + 1], py);
                unsafeAtomicAdd(&dipole[mol * 3 + 2], pz);
            }
        }
    }
}

// ---------------------------------------------------------------------------
extern "C" void kernel_launch(void* const* d_in, const int* in_sizes, int n_in,
                              void* d_out, int out_size, void* d_ws, size_t ws_size,
                              hipStream_t stream)
{
    const float* cart       = (const float*)d_in[0];
    const float* shifts     = (const float*)d_in[1];
    const float* centers    = (const float*)d_in[2];
    const float* widths     = (const float*)d_in[3];
    const float* c_emb      = (const float*)d_in[4];
    const float* W1         = (const float*)d_in[5];
    const float* b1         = (const float*)d_in[6];
    const float* W2         = (const float*)d_in[7];
    const float* b2         = (const float*)d_in[8];
    const int*   species    = (const int*)d_in[10];
    const int*   atom_index = (const int*)d_in[11];

    // ws: tv_part(1.5MB) | cnt(512KB) | soff_g(512KB) | rec(5MB)
    float*    tv_part = (float*)d_ws;
    unsigned* cnt     = (unsigned*)(tv_part + (size_t)NMOL * NSUB * NATOM * 3);
    unsigned* soff_g  = cnt + (size_t)TOTNATOM * NSUB;
    float2*   rec     = (float2*)(soff_g + (size_t)NMOL * NSUB * NATOM);
    float*    dipole  = (float*)d_out;
    int       ndip    = out_size;

    void* args[] = {
        (void*)&cart, (void*)&shifts, (void*)&centers, (void*)&widths,
        (void*)&c_emb, (void*)&species, (void*)&atom_index,
        (void*)&W1, (void*)&b1, (void*)&W2, (void*)&b2,
        (void*)&cnt, (void*)&soff_g, (void*)&rec, (void*)&tv_part,
        (void*)&dipole, (void*)&ndip
    };
    hipLaunchCooperativeKernel((void*)fused_kernel, dim3(NMOL * NSUB), dim3(1024),
                               args, 0, stream);
}

// Round 26
// 101.919 us; speedup vs baseline: 2.1791x; 1.5835x over previous
//
#include <hip/hip_runtime.h>

#define NMOL   32
#define NATOM  512
#define NPAIR  32768
#define NB     64
#define HIDDEN 256
#define TOTNATOM (NMOL * NATOM)
#define NSUB   8
#define BLKCAP 2560
#define ABLK   8
#define SLOTS  128
#define SREP   16

typedef __attribute__((ext_vector_type(8))) short bf16x8;
typedef __attribute__((ext_vector_type(4))) float f32x4;

__device__ __forceinline__ unsigned short f2bf(float x) {   // RNE f32->bf16
    unsigned u = __float_as_uint(x);
    u += 0x7FFFu + ((u >> 16) & 1u);
    return (unsigned short)(u >> 16);
}

// ---------------------------------------------------------------------------
// K1 scatter (production): R23 + rtn-position (pass-1 atomicAdd return value
// is the within-atom record ordinal -> pcnt pass-2 atomics deleted).
// ---------------------------------------------------------------------------
__global__ __launch_bounds__(1024) void scatter_kernel(
    const float* __restrict__ cart, const float* __restrict__ shifts,
    const int* __restrict__ species, const int* __restrict__ atom_index,
    unsigned* __restrict__ cnt, unsigned* __restrict__ soff_g,
    float2* __restrict__ rec, float* __restrict__ tv_part,
    float* __restrict__ dipole, int ndip)
{
    __shared__ float    tv_sc[NATOM * 3];
    __shared__ float    s_cart[NATOM * 3];
    __shared__ int      s_sp[NATOM];
    __shared__ unsigned lcnt[NATOM];
    __shared__ unsigned pref[NATOM];
    __shared__ unsigned stot;
    __shared__ float2   list[BLKCAP];

    const int tid  = threadIdx.x;
    const int lane = tid & 63;
    const int wave = tid >> 6;
    const int b    = blockIdx.x;
    const int mol  = b >> 3;
    const int sub  = b & 7;

    if (b == 0 && tid < ndip) dipole[tid] = 0.f;

    const float* cm = cart + (size_t)mol * NATOM * 3;
    const int*   sp = species + (size_t)mol * NATOM;
    for (int i = tid; i < NATOM * 3; i += 1024) { tv_sc[i] = 0.f; s_cart[i] = cm[i]; }
    if (tid < NATOM) { lcnt[tid] = 0u; s_sp[tid] = sp[tid]; }
    __syncthreads();

    const int* ai0 = atom_index + (size_t)mol * NPAIR;
    const int* ai1 = ai0 + (size_t)NMOL * NPAIR;
    const float* sh = shifts + (size_t)mol * NPAIR * 3;
    const int base = sub * 4096;

    int   gi0[4], gi1[4];
    float gsx[4], gsy[4], gsz[4];
#pragma unroll
    for (int k = 0; k < 4; ++k) {
        const int p = base + k * 1024 + tid;
        gi0[k] = ai0[p];
        gi1[k] = ai1[p];
        gsx[k] = sh[p * 3 + 0];
        gsy[k] = sh[p * 3 + 1];
        gsz[k] = sh[p * 3 + 2];
    }

    float    rd[4];
    unsigned rf[4], rp[4];
    int      ri[4];
#pragma unroll
    for (int k = 0; k < 4; ++k) {
        const int a3 = gi0[k] * 3, b3 = gi1[k] * 3;
        const float m = (gsx[k] > -1e10f && gsy[k] > -1e10f && gsz[k] > -1e10f)
                        ? 1.f : 0.f;
        const float dx = (s_cart[a3 + 0] - s_cart[b3 + 0] + gsx[k]) * m;
        const float dy = (s_cart[a3 + 1] - s_cart[b3 + 1] + gsy[k]) * m;
        const float dz = (s_cart[a3 + 2] - s_cart[b3 + 2] + gsz[k]) * m;
        unsafeAtomicAdd(&tv_sc[a3 + 0], dx);
        unsafeAtomicAdd(&tv_sc[a3 + 1], dy);
        unsafeAtomicAdd(&tv_sc[a3 + 2], dz);
        const float d = sqrtf(dx * dx + dy * dy + dz * dz + 1e-12f);
        ri[k] = -1;
        if (d < 5.0f && m != 0.f) {
            const float fc = 0.5f * (__cosf(0.62831853071795864769f * d) + 1.f);
            rd[k] = d;
            rf[k] = (__float_as_uint(fc) & ~7u) | (unsigned)s_sp[gi1[k]];
            ri[k] = gi0[k];
            rp[k] = atomicAdd(&lcnt[gi0[k]], 1u);   // rtn = within-atom ordinal
        }
    }
    __syncthreads();

    if (wave == 0) {                           // single-wave exclusive scan
        unsigned c[8], s = 0;
#pragma unroll
        for (int j = 0; j < 8; ++j) { c[j] = lcnt[lane * 8 + j]; s += c[j]; }
        unsigned incl = s;
#pragma unroll
        for (int off = 1; off < 64; off <<= 1) {
            const unsigned v = __shfl_up(incl, off);
            if (lane >= off) incl += v;
        }
        unsigned run = incl - s;
#pragma unroll
        for (int j = 0; j < 8; ++j) { pref[lane * 8 + j] = run; run += c[j]; }
        if (lane == 63) stot = incl;
    }
    __syncthreads();

#pragma unroll
    for (int k = 0; k < 4; ++k) {              // pass 2: pure divergent writes
        if (ri[k] >= 0) {
            const unsigned idx = pref[ri[k]] + rp[k];
            if (idx < (unsigned)BLKCAP)
                list[idx] = make_float2(rd[k], __uint_as_float(rf[k]));
        }
    }
    __syncthreads();

    const int tot = min((int)stot, BLKCAP);
    float2* dstr = rec + (size_t)b * BLKCAP;
    for (int i = tid; i < tot; i += 1024) dstr[i] = list[i];

    if (tid < NATOM) {
        cnt[((size_t)mol * NATOM + tid) * NSUB + sub] = lcnt[tid];
        soff_g[(size_t)b * NATOM + tid] = pref[tid];
    }
    float* tg = tv_part + (size_t)b * NATOM * 3;
    for (int i = tid; i < NATOM * 3; i += 1024) tg[i] = tv_sc[i];
}

// ---------------------------------------------------------------------------
// SHADOW noTV: identical to production scatter MINUS the 3 tv ds_add_f32
// (tv_sc still zeroed + stored, so only the atomic cost is ablated).
// reps=16 amplified, scratch outputs. Readout: tv_cost = 20.6 - dur/16.
// ---------------------------------------------------------------------------
__global__ __launch_bounds__(1024) void scat_noTV_kernel(
    const float* __restrict__ cart, const float* __restrict__ shifts,
    const int* __restrict__ species, const int* __restrict__ atom_index,
    unsigned* __restrict__ cnt, unsigned* __restrict__ soff_g,
    float2* __restrict__ rec, float* __restrict__ tv_part, int reps)
{
    __shared__ float    tv_sc[NATOM * 3];
    __shared__ float    s_cart[NATOM * 3];
    __shared__ int      s_sp[NATOM];
    __shared__ unsigned lcnt[NATOM];
    __shared__ unsigned pref[NATOM];
    __shared__ unsigned stot;
    __shared__ float2   list[BLKCAP];

    const int tid  = threadIdx.x;
    const int lane = tid & 63;
    const int wave = tid >> 6;
    const int b    = blockIdx.x;
    const int mol  = b >> 3;
    const int sub  = b & 7;

    const float* cm = cart + (size_t)mol * NATOM * 3;
    const int*   sp = species + (size_t)mol * NATOM;
    for (int i = tid; i < NATOM * 3; i += 1024) s_cart[i] = cm[i];
    if (tid < NATOM) s_sp[tid] = sp[tid];

    const int* ai0 = atom_index + (size_t)mol * NPAIR;
    const int* ai1 = ai0 + (size_t)NMOL * NPAIR;
    const float* sh = shifts + (size_t)mol * NPAIR * 3;
    const int base = sub * 4096;

    for (int rep = 0; rep < reps; ++rep) {
        __syncthreads();
        for (int i = tid; i < NATOM * 3; i += 1024) tv_sc[i] = 0.f;
        if (tid < NATOM) lcnt[tid] = 0u;
        __syncthreads();

        int   gi0[4], gi1[4];
        float gsx[4], gsy[4], gsz[4];
#pragma unroll
        for (int k = 0; k < 4; ++k) {
            const int p = base + k * 1024 + tid;
            gi0[k] = ai0[p];
            gi1[k] = ai1[p];
            gsx[k] = sh[p * 3 + 0];
            gsy[k] = sh[p * 3 + 1];
            gsz[k] = sh[p * 3 + 2];
        }

        float    rd[4];
        unsigned rf[4], rp[4];
        int      ri[4];
#pragma unroll
        for (int k = 0; k < 4; ++k) {
            const int a3 = gi0[k] * 3, b3 = gi1[k] * 3;
            const float m = (gsx[k] > -1e10f && gsy[k] > -1e10f && gsz[k] > -1e10f)
                            ? 1.f : 0.f;
            const float dx = (s_cart[a3 + 0] - s_cart[b3 + 0] + gsx[k]) * m;
            const float dy = (s_cart[a3 + 1] - s_cart[b3 + 1] + gsy[k]) * m;
            const float dz = (s_cart[a3 + 2] - s_cart[b3 + 2] + gsz[k]) * m;
            // (3 tv ds_add_f32 DELETED -- the only ablation)
            const float d = sqrtf(dx * dx + dy * dy + dz * dz + 1e-12f);
            ri[k] = -1;
            if (d < 5.0f && m != 0.f) {
                const float fc = 0.5f * (__cosf(0.62831853071795864769f * d) + 1.f);
                rd[k] = d;
                rf[k] = (__float_as_uint(fc) & ~7u) | (unsigned)s_sp[gi1[k]];
                ri[k] = gi0[k];
                rp[k] = atomicAdd(&lcnt[gi0[k]], 1u);
            }
        }
        __syncthreads();

        if (wave == 0) {
            unsigned c[8], s = 0;
#pragma unroll
            for (int j = 0; j < 8; ++j) { c[j] = lcnt[lane * 8 + j]; s += c[j]; }
            unsigned incl = s;
#pragma unroll
            for (int off = 1; off < 64; off <<= 1) {
                const unsigned v = __shfl_up(incl, off);
                if (lane >= off) incl += v;
            }
            unsigned run = incl - s;
#pragma unroll
            for (int j = 0; j < 8; ++j) { pref[lane * 8 + j] = run; run += c[j]; }
            if (lane == 63) stot = incl;
        }
        __syncthreads();

#pragma unroll
        for (int k = 0; k < 4; ++k) {
            if (ri[k] >= 0) {
                const unsigned idx = pref[ri[k]] + rp[k];
                if (idx < (unsigned)BLKCAP)
                    list[idx] = make_float2(rd[k], __uint_as_float(rf[k]));
            }
        }
        __syncthreads();

        const int tot = min((int)stot, BLKCAP);
        float2* dstr = rec + (size_t)b * BLKCAP;
        for (int i = tid; i < tot; i += 1024) dstr[i] = list[i];
        if (tid < NATOM) {
            cnt[((size_t)mol * NATOM + tid) * NSUB + sub] = lcnt[tid];
            soff_g[(size_t)b * NATOM + tid] = pref[tid];
        }
        float* tg = tv_part + (size_t)b * NATOM * 3;
        for (int i = tid; i < NATOM * 3; i += 1024) tg[i] = tv_sc[i];
    }
}

// ---------------------------------------------------------------------------
// K2 gather: verbatim R23.
// ---------------------------------------------------------------------------
__global__ __launch_bounds__(256) void gather_kernel(
    const unsigned* __restrict__ cnt, const unsigned* __restrict__ soff_g,
    const float2* __restrict__ rec,
    const float* __restrict__ centers, const float* __restrict__ widths,
    const float* __restrict__ c_emb, const float* __restrict__ tv_part,
    unsigned short* __restrict__ dens_bf, float* __restrict__ tvv)
{
    __shared__ float    cemb[8 * NB];
    __shared__ float2   list[ABLK][SLOTS];
    __shared__ unsigned scnt[ABLK][NSUB];
    __shared__ unsigned sofg[ABLK][NSUB];
    __shared__ unsigned soff[ABLK][NSUB];
    __shared__ unsigned mtot[ABLK];

    const int tid = threadIdx.x;
    const int a0  = blockIdx.x * ABLK;
    const int mol = a0 >> 9;
    const int ra0 = a0 & 511;

    for (int i = tid; i < 8 * NB; i += 256) cemb[i] = c_emb[i];
    if (tid < ABLK * NSUB) {
        const int al = tid >> 3, s = tid & 7;
        scnt[al][s] = cnt[(size_t)(a0 + al) * NSUB + s];
        sofg[al][s] = soff_g[(size_t)(mol * NSUB + s) * NATOM + (ra0 + al)];
    }
    __syncthreads();

    if (tid < ABLK) {
        int o = 0;
#pragma unroll
        for (int s = 0; s < NSUB; ++s) {
            soff[tid][s] = (unsigned)o;
            o += min((int)scnt[tid][s], SLOTS - o);
        }
        const int mp = (o + 7) & ~7;
        mtot[tid] = (unsigned)mp;
        for (int k = o; k < mp; ++k) list[tid][k] = make_float2(0.f, 0.f);
    }
    __syncthreads();

    {
        const int seg = tid >> 2;
        const int prt = tid & 3;
        const int al = seg >> 3, s = seg & 7;
        const int off = (int)soff[al][s];
        const int n = min((int)scnt[al][s], SLOTS - off);
        const float2* src = rec + (size_t)(mol * NSUB + s) * BLKCAP + sofg[al][s];
        float2* dst = &list[al][off];
        const int k0 = prt * 5, k1 = min(k0 + 5, n);
        for (int k = k0; k < k1; ++k) dst[k] = src[k];
    }
    if (tid < ABLK * 3) {
        const int al = tid / 3, c = tid - al * 3;
        float s = 0.f;
#pragma unroll
        for (int sb = 0; sb < NSUB; ++sb)
            s += tv_part[((size_t)(mol * NSUB + sb) * NATOM + (ra0 + al)) * 3 + c];
        tvv[(size_t)(a0 + al) * 3 + c] = s;
    }
    __syncthreads();

    const int lane = tid & 63;
    const int wave = tid >> 6;
    const float L2E = 1.4426950408889634f;
    const float wl  = widths[lane];
    const float cl  = centers[lane];
    const float e2  = -wl * L2E;
    const float b2  = 2.f * wl * cl * L2E;
    const float a2  = -wl * cl * cl * L2E;

#define REC1(A, dv, fv) { const unsigned f_ = __float_as_uint(fv);           \
        const float v_ = fmaf(dv, fmaf(dv, e2, b2), a2);                     \
        A = fmaf(exp2f(v_) * __uint_as_float(f_ & ~7u),                      \
                 cemb[((f_ & 7u) << 6) | lane], A); }

    for (int al = wave; al < ABLK; al += 4) {
        const int m = (int)mtot[al];
        const float4* l4 = reinterpret_cast<const float4*>(list[al]);
        float acc0 = 0.f, acc1 = 0.f;
        for (int j = 0; j < m; j += 8) {
            const float4 q0 = l4[(j >> 1) + 0];
            const float4 q1 = l4[(j >> 1) + 1];
            const float4 q2 = l4[(j >> 1) + 2];
            const float4 q3 = l4[(j >> 1) + 3];
            REC1(acc0, q0.x, q0.y) REC1(acc1, q0.z, q0.w)
            REC1(acc0, q1.x, q1.y) REC1(acc1, q1.z, q1.w)
            REC1(acc0, q2.x, q2.y) REC1(acc1, q2.z, q2.w)
            REC1(acc0, q3.x, q3.y) REC1(acc1, q3.z, q3.w)
        }
        dens_bf[(size_t)(a0 + al) * NB + lane] = f2bf(acc0 + acc1);
    }
#undef REC1
}

// ---------------------------------------------------------------------------
// K3 nn via MFMA: verbatim R23.
// ---------------------------------------------------------------------------
__global__ __launch_bounds__(256) void nn_kernel(
    const unsigned short* __restrict__ dens_bf, const float* __restrict__ tvv,
    const float* __restrict__ W1, const float* __restrict__ b1,
    const float* __restrict__ W2, const float* __restrict__ b2,
    float* __restrict__ dipole)
{
    __shared__ __align__(16) unsigned short w1t[HIDDEN * 72];
    __shared__ float b1_l[HIDDEN], w2_l[HIDDEN];
    __shared__ float sred[4][4][3];

    const int tid = threadIdx.x;
    const int mol = blockIdx.x >> 3;

    for (int i = tid; i < NB * HIDDEN; i += 256) {
        const int k = i >> 8, j = i & 255;
        w1t[j * 72 + k] = f2bf(W1[i]);
    }
    if (tid < HIDDEN) { b1_l[tid] = b1[tid]; w2_l[tid] = W2[tid]; }
    __syncthreads();

    const int lane = tid & 63;
    const int wave = tid >> 6;
    const int fr   = lane & 15;
    const int fg   = lane >> 4;
    const int a0w  = blockIdx.x * 64 + wave * 16;

    bf16x8 afr[2];
#pragma unroll
    for (int kk = 0; kk < 2; ++kk)
        afr[kk] = *reinterpret_cast<const bf16x8*>(
            dens_bf + (size_t)(a0w + fr) * NB + kk * 32 + fg * 8);

    float sdip[4] = {0.f, 0.f, 0.f, 0.f};
#pragma unroll
    for (int nt = 0; nt < 16; ++nt) {
        const bf16x8 bf0 = *reinterpret_cast<const bf16x8*>(
            &w1t[(nt * 16 + fr) * 72 + 0 + fg * 8]);
        const bf16x8 bf1 = *reinterpret_cast<const bf16x8*>(
            &w1t[(nt * 16 + fr) * 72 + 32 + fg * 8]);
        f32x4 acc = {0.f, 0.f, 0.f, 0.f};
        acc = __builtin_amdgcn_mfma_f32_16x16x32_bf16(afr[0], bf0, acc, 0, 0, 0);
        acc = __builtin_amdgcn_mfma_f32_16x16x32_bf16(afr[1], bf1, acc, 0, 0, 0);
        const int j = nt * 16 + fr;
        const float b1v = b1_l[j], w2v = w2_l[j];
#pragma unroll
        for (int i = 0; i < 4; ++i) {
            const float h = acc[i] + b1v;
            sdip[i] += (h / (1.f + __expf(-h))) * w2v;
        }
    }
#pragma unroll
    for (int off = 1; off < 16; off <<= 1) {
#pragma unroll
        for (int i = 0; i < 4; ++i) sdip[i] += __shfl_xor(sdip[i], off);
    }
    if (fr == 0) {
        const float b2v = b2[0];
        float px = 0.f, py = 0.f, pz = 0.f;
#pragma unroll
        for (int i = 0; i < 4; ++i) {
            const int a = a0w + fg * 4 + i;
            const float out = sdip[i] + b2v;
            px += out * tvv[a * 3 + 0];
            py += out * tvv[a * 3 + 1];
            pz += out * tvv[a * 3 + 2];
        }
        sred[wave][fg][0] = px; sred[wave][fg][1] = py; sred[wave][fg][2] = pz;
    }
    __syncthreads();
    if (tid < 3) {
        float s = 0.f;
#pragma unroll
        for (int w = 0; w < 4; ++w)
#pragma unroll
            for (int g = 0; g < 4; ++g) s += sred[w][g][tid];
        unsafeAtomicAdd(&dipole[mol * 3 + tid], s);
    }
}

// ---------------------------------------------------------------------------
extern "C" void kernel_launch(void* const* d_in, const int* in_sizes, int n_in,
                              void* d_out, int out_size, void* d_ws, size_t ws_size,
                              hipStream_t stream)
{
    const float* cart       = (const float*)d_in[0];
    const float* shifts     = (const float*)d_in[1];
    const float* centers    = (const float*)d_in[2];
    const float* widths     = (const float*)d_in[3];
    const float* c_emb      = (const float*)d_in[4];
    const float* W1         = (const float*)d_in[5];
    const float* b1         = (const float*)d_in[6];
    const float* W2         = (const float*)d_in[7];
    const float* b2         = (const float*)d_in[8];
    const int*   species    = (const int*)d_in[10];
    const int*   atom_index = (const int*)d_in[11];

    // production ws
    float*          tv_part = (float*)d_ws;
    unsigned*       cnt     = (unsigned*)(tv_part + (size_t)NMOL * NSUB * NATOM * 3);
    unsigned*       soff_g  = cnt + (size_t)TOTNATOM * NSUB;
    float*          tvv     = (float*)(soff_g + (size_t)NMOL * NSUB * NATOM);
    unsigned short* dens_bf = (unsigned short*)(tvv + (size_t)TOTNATOM * 3);
    float2*         rec     = (float2*)(dens_bf + (size_t)TOTNATOM * NB);
    // shadow scratch (disjoint)
    float*          tv2     = (float*)(rec + (size_t)NMOL * NSUB * BLKCAP);
    unsigned*       cnt2    = (unsigned*)(tv2 + (size_t)NMOL * NSUB * NATOM * 3);
    unsigned*       soff2   = cnt2 + (size_t)TOTNATOM * NSUB;
    float2*         rec2    = (float2*)(soff2 + (size_t)NMOL * NSUB * NATOM);
    float*          dipole  = (float*)d_out;

    hipLaunchKernelGGL(scatter_kernel, dim3(NMOL * NSUB), dim3(1024), 0, stream,
                       cart, shifts, species, atom_index, cnt, soff_g, rec,
                       tv_part, dipole, out_size);
    hipLaunchKernelGGL(gather_kernel, dim3(TOTNATOM / ABLK), dim3(256), 0, stream,
                       cnt, soff_g, rec, centers, widths, c_emb, tv_part,
                       dens_bf, tvv);
    hipLaunchKernelGGL(nn_kernel, dim3(TOTNATOM / 64), dim3(256), 0, stream,
                       dens_bf, tvv, W1, b1, W2, b2, dipole);
    // diagnostic shadow (scratch only, after the real pipeline)
    hipLaunchKernelGGL(scat_noTV_kernel, dim3(NMOL * NSUB), dim3(1024), 0, stream,
                       cart, shifts, species, atom_index, cnt2, soff2, rec2,
                       tv2, SREP);
}

// Round 27
// 46.079 us; speedup vs baseline: 4.8198x; 2.2118x over previous
//
#include <hip/hip_runtime.h>

#define NMOL   32
#define NATOM  512
#define NPAIR  32768
#define NB     64
#define HIDDEN 256
#define TOTNATOM (NMOL * NATOM)
#define NSUB   8
#define BLKCAP4 4352   // all-valid records/block (exactly 4096 + slack)
#define ABLK   8
#define NSLOT  128     // per-atom record slots in gather (lambda 64, +8 sigma)
#define CSLOT  64      // per-atom compacted in-cutoff slots (lambda 17, +11 sigma)

typedef __attribute__((ext_vector_type(8))) short bf16x8;
typedef __attribute__((ext_vector_type(4))) float f32x4;

__device__ __forceinline__ unsigned short f2bf(float x) {   // RNE f32->bf16
    unsigned u = __float_as_uint(x);
    u += 0x7FFFu + ((u >> 16) & 1u);
    return (unsigned short)(u >> 16);
}

// ---------------------------------------------------------------------------
// K1 scatter: R26-measured noTV form (3.5us/rep) extended to 16B all-valid
// records {dx,dy,dz,spc}. NO tv atomics (R26 ablation: the 3 ds_add_f32 were
// ~17us of 20.6 -- LDS atomic throughput ~1 lane-op/3cyc/CU). tv moves to
// gather as a shuffle reduction. Only remaining atomic: lcnt (1M lane-ops).
// ---------------------------------------------------------------------------
__global__ __launch_bounds__(1024) void scatter_kernel(
    const float* __restrict__ cart, const float* __restrict__ shifts,
    const int* __restrict__ species, const int* __restrict__ atom_index,
    unsigned* __restrict__ cnt, unsigned* __restrict__ soff_g,
    float4* __restrict__ rec, float* __restrict__ dipole, int ndip)
{
    __shared__ float    s_cart[NATOM * 3];  // 6 KB
    __shared__ int      s_sp[NATOM];        // 2 KB
    __shared__ unsigned lcnt[NATOM];        // 2 KB
    __shared__ unsigned pref[NATOM];        // 2 KB
    __shared__ unsigned stot;
    __shared__ float4   list[BLKCAP4];      // 68 KB (1 block/CU, as before)

    const int tid  = threadIdx.x;
    const int lane = tid & 63;
    const int wave = tid >> 6;
    const int b    = blockIdx.x;
    const int mol  = b >> 3;
    const int sub  = b & 7;

    if (b == 0 && tid < ndip) dipole[tid] = 0.f;

    const float* cm = cart + (size_t)mol * NATOM * 3;
    const int*   sp = species + (size_t)mol * NATOM;
    for (int i = tid; i < NATOM * 3; i += 1024) s_cart[i] = cm[i];
    if (tid < NATOM) { lcnt[tid] = 0u; s_sp[tid] = sp[tid]; }
    __syncthreads();

    const int* ai0 = atom_index + (size_t)mol * NPAIR;
    const int* ai1 = ai0 + (size_t)NMOL * NPAIR;
    const float* sh = shifts + (size_t)mol * NPAIR * 3;
    const int base = sub * 4096;

    int   gi0[4], gi1[4];
    float gsx[4], gsy[4], gsz[4];
#pragma unroll
    for (int k = 0; k < 4; ++k) {              // batched global loads
        const int p = base + k * 1024 + tid;
        gi0[k] = ai0[p];
        gi1[k] = ai1[p];
        gsx[k] = sh[p * 3 + 0];
        gsy[k] = sh[p * 3 + 1];
        gsz[k] = sh[p * 3 + 2];
    }

    float    rx[4], ry[4], rz[4];
    unsigned rs[4], rp[4];
    int      ri[4];
#pragma unroll
    for (int k = 0; k < 4; ++k) {
        const int a3 = gi0[k] * 3, b3 = gi1[k] * 3;
        const bool m = (gsx[k] > -1e10f && gsy[k] > -1e10f && gsz[k] > -1e10f);
        ri[k] = -1;
        if (m) {                               // masked pairs contribute nothing
            rx[k] = s_cart[a3 + 0] - s_cart[b3 + 0] + gsx[k];
            ry[k] = s_cart[a3 + 1] - s_cart[b3 + 1] + gsy[k];
            rz[k] = s_cart[a3 + 2] - s_cart[b3 + 2] + gsz[k];
            rs[k] = (unsigned)s_sp[gi1[k]];
            ri[k] = gi0[k];
            rp[k] = atomicAdd(&lcnt[gi0[k]], 1u);   // rtn = within-atom ordinal
        }
    }
    __syncthreads();

    if (wave == 0) {                           // single-wave exclusive scan
        unsigned c[8], s = 0;
#pragma unroll
        for (int j = 0; j < 8; ++j) { c[j] = lcnt[lane * 8 + j]; s += c[j]; }
        unsigned incl = s;
#pragma unroll
        for (int off = 1; off < 64; off <<= 1) {
            const unsigned v = __shfl_up(incl, off);
            if (lane >= off) incl += v;
        }
        unsigned run = incl - s;
#pragma unroll
        for (int j = 0; j < 8; ++j) { pref[lane * 8 + j] = run; run += c[j]; }
        if (lane == 63) stot = incl;
    }
    __syncthreads();

#pragma unroll
    for (int k = 0; k < 4; ++k) {              // pass 2: divergent plain writes
        if (ri[k] >= 0) {
            const unsigned idx = pref[ri[k]] + rp[k];
            if (idx < (unsigned)BLKCAP4)
                list[idx] = make_float4(rx[k], ry[k], rz[k], __uint_as_float(rs[k]));
        }
    }
    __syncthreads();

    const int tot = min((int)stot, BLKCAP4);   // coalesced sweep
    float4* dstr = rec + (size_t)b * BLKCAP4;
    for (int i = tid; i < tot; i += 1024) dstr[i] = list[i];

    if (tid < NATOM) {
        cnt[((size_t)mol * NATOM + tid) * NSUB + sub] = lcnt[tid];
        soff_g[(size_t)b * NATOM + tid] = pref[tid];
    }
}

// ---------------------------------------------------------------------------
// K2 gather: 2048 blocks x 256 thr, 8 atoms/block.
//  phase A (lane=record, parallel): coalesced LDS float4 reads -> tv partials
//    + d + fc; ballot-compact in-cutoff {d, fc|spc} -> cbuf; tv shuffle-reduce
//    -> tvv (atomic-free; tv_part machinery deleted).
//  phase B (lane=basis): verbatim quadratic-exponent REC1 over cbuf.
// ---------------------------------------------------------------------------
__global__ __launch_bounds__(256) void gather_kernel(
    const unsigned* __restrict__ cnt, const unsigned* __restrict__ soff_g,
    const float4* __restrict__ rec,
    const float* __restrict__ centers, const float* __restrict__ widths,
    const float* __restrict__ c_emb,
    unsigned short* __restrict__ dens_bf, float* __restrict__ tvv)
{
    __shared__ float    cemb[8 * NB];          // 2 KB
    __shared__ float4   list4[ABLK][NSLOT];    // 16 KB
    __shared__ float2   cbuf[ABLK][CSLOT];     // 4 KB
    __shared__ unsigned scnt[ABLK][NSUB];
    __shared__ unsigned sofg[ABLK][NSUB];
    __shared__ unsigned soff[ABLK][NSUB];
    __shared__ unsigned ntot[ABLK];

    const int tid = threadIdx.x;
    const int a0  = blockIdx.x * ABLK;
    const int mol = a0 >> 9;
    const int ra0 = a0 & 511;

    for (int i = tid; i < 8 * NB; i += 256) cemb[i] = c_emb[i];
    if (tid < ABLK * NSUB) {
        const int al = tid >> 3, s = tid & 7;
        scnt[al][s] = cnt[(size_t)(a0 + al) * NSUB + s];
        sofg[al][s] = soff_g[(size_t)(mol * NSUB + s) * NATOM + (ra0 + al)];
    }
    __syncthreads();

    if (tid < ABLK) {                          // per-atom prefix over 8 segs
        int o = 0;
#pragma unroll
        for (int s = 0; s < NSUB; ++s) {
            soff[tid][s] = (unsigned)o;
            o += min((int)scnt[tid][s], NSLOT - o);
        }
        ntot[tid] = (unsigned)o;               // exact count (<=128)
    }
    __syncthreads();

    {   // segment copy: 4 threads per (atom, sub) segment; ROBUST stride loop
        const int seg = tid >> 2;              // 0..63
        const int prt = tid & 3;
        const int al = seg >> 3, s = seg & 7;
        const int off = (int)soff[al][s];
        const int n = min((int)scnt[al][s], NSLOT - off);
        const float4* src = rec + (size_t)(mol * NSUB + s) * BLKCAP4 + sofg[al][s];
        float4* dst = &list4[al][off];
        for (int k = prt; k < n; k += 4) dst[k] = src[k];
    }
    __syncthreads();

    const int lane = tid & 63;
    const int wave = tid >> 6;

    const float L2E = 1.4426950408889634f;
    const float wl  = widths[lane];
    const float cl  = centers[lane];
    const float qe  = -wl * L2E;
    const float qb  = 2.f * wl * cl * L2E;
    const float qa  = -wl * cl * cl * L2E;

    for (int al = wave; al < ABLK; al += 4) {  // wave handles 2 atoms
        const int n = (int)ntot[al];
        const int a = a0 + al;

        // ---- phase A: lane = record ----
        float tx = 0.f, ty = 0.f, tz = 0.f;
        int mbase = 0;
        for (int c0 = 0; c0 < n; c0 += 64) {
            const int k = c0 + lane;
            const bool valid = (k < n);
            float4 q = make_float4(0.f, 0.f, 0.f, 0.f);
            if (valid) q = list4[al][k];
            tx += q.x; ty += q.y; tz += q.z;
            const float d = sqrtf(q.x * q.x + q.y * q.y + q.z * q.z + 1e-12f);
            const bool in = valid && (d < 5.0f);
            const unsigned long long mask = __ballot(in);
            if (in) {
                const float fc = 0.5f * (__cosf(0.62831853071795864769f * d) + 1.f);
                const unsigned fb = (__float_as_uint(fc) & ~7u)
                                  | (__float_as_uint(q.w) & 7u);
                const int pos = __builtin_amdgcn_mbcnt_hi((unsigned)(mask >> 32),
                              __builtin_amdgcn_mbcnt_lo((unsigned)mask, 0u));
                const int idx = mbase + pos;
                if (idx < CSLOT) cbuf[al][idx] = make_float2(d, __uint_as_float(fb));
            }
            mbase += (int)__popcll(mask);
        }
        if (mbase > CSLOT) mbase = CSLOT;
        const int mp = (mbase + 7) & ~7;       // pad to multiple of 8
        if (lane < mp - mbase) cbuf[al][mbase + lane] = make_float2(0.f, 0.f);
        // tv reduce over the wave
#pragma unroll
        for (int off = 32; off; off >>= 1) {
            tx += __shfl_down(tx, off);
            ty += __shfl_down(ty, off);
            tz += __shfl_down(tz, off);
        }
        if (lane == 0) {
            tvv[(size_t)a * 3 + 0] = tx;
            tvv[(size_t)a * 3 + 1] = ty;
            tvv[(size_t)a * 3 + 2] = tz;
        }
        // (same wave wrote cbuf; compiler inserts lgkmcnt -- no barrier needed)

        // ---- phase B: lane = basis ----
#define REC1(A, dv, fv) { const unsigned f_ = __float_as_uint(fv);           \
        const float v_ = fmaf(dv, fmaf(dv, qe, qb), qa);                     \
        A = fmaf(exp2f(v_) * __uint_as_float(f_ & ~7u),                      \
                 cemb[((f_ & 7u) << 6) | lane], A); }
        const float4* l4 = reinterpret_cast<const float4*>(cbuf[al]);
        float acc0 = 0.f, acc1 = 0.f;
        for (int j = 0; j < mp; j += 8) {
            const float4 q0 = l4[(j >> 1) + 0];
            const float4 q1 = l4[(j >> 1) + 1];
            const float4 q2 = l4[(j >> 1) + 2];
            const float4 q3 = l4[(j >> 1) + 3];
            REC1(acc0, q0.x, q0.y) REC1(acc1, q0.z, q0.w)
            REC1(acc0, q1.x, q1.y) REC1(acc1, q1.z, q1.w)
            REC1(acc0, q2.x, q2.y) REC1(acc1, q2.z, q2.w)
            REC1(acc0, q3.x, q3.y) REC1(acc1, q3.z, q3.w)
        }
#undef REC1
        dens_bf[(size_t)a * NB + lane] = f2bf(acc0 + acc1);
    }
}

// ---------------------------------------------------------------------------
// K3 nn via MFMA: verbatim R23/R26 (dipole atomics folded in).
// ---------------------------------------------------------------------------
__global__ __launch_bounds__(256) void nn_kernel(
    const unsigned short* __restrict__ dens_bf, const float* __restrict__ tvv,
    const float* __restrict__ W1, const float* __restrict__ b1,
    const float* __restrict__ W2, const float* __restrict__ b2,
    float* __restrict__ dipole)
{
    __shared__ __align__(16) unsigned short w1t[HIDDEN * 72];
    __shared__ float b1_l[HIDDEN], w2_l[HIDDEN];
    __shared__ float sred[4][4][3];

    const int tid = threadIdx.x;
    const int mol = blockIdx.x >> 3;

    for (int i = tid; i < NB * HIDDEN; i += 256) {
        const int k = i >> 8, j = i & 255;
        w1t[j * 72 + k] = f2bf(W1[i]);
    }
    if (tid < HIDDEN) { b1_l[tid] = b1[tid]; w2_l[tid] = W2[tid]; }
    __syncthreads();

    const int lane = tid & 63;
    const int wave = tid >> 6;
    const int fr   = lane & 15;
    const int fg   = lane >> 4;
    const int a0w  = blockIdx.x * 64 + wave * 16;

    bf16x8 afr[2];
#pragma unroll
    for (int kk = 0; kk < 2; ++kk)
        afr[kk] = *reinterpret_cast<const bf16x8*>(
            dens_bf + (size_t)(a0w + fr) * NB + kk * 32 + fg * 8);

    float sdip[4] = {0.f, 0.f, 0.f, 0.f};
#pragma unroll
    for (int nt = 0; nt < 16; ++nt) {
        const bf16x8 bf0 = *reinterpret_cast<const bf16x8*>(
            &w1t[(nt * 16 + fr) * 72 + 0 + fg * 8]);
        const bf16x8 bf1 = *reinterpret_cast<const bf16x8*>(
            &w1t[(nt * 16 + fr) * 72 + 32 + fg * 8]);
        f32x4 acc = {0.f, 0.f, 0.f, 0.f};
        acc = __builtin_amdgcn_mfma_f32_16x16x32_bf16(afr[0], bf0, acc, 0, 0, 0);
        acc = __builtin_amdgcn_mfma_f32_16x16x32_bf16(afr[1], bf1, acc, 0, 0, 0);
        const int j = nt * 16 + fr;
        const float b1v = b1_l[j], w2v = w2_l[j];
#pragma unroll
        for (int i = 0; i < 4; ++i) {
            const float h = acc[i] + b1v;
            sdip[i] += (h / (1.f + __expf(-h))) * w2v;
        }
    }
#pragma unroll
    for (int off = 1; off < 16; off <<= 1) {
#pragma unroll
        for (int i = 0; i < 4; ++i) sdip[i] += __shfl_xor(sdip[i], off);
    }
    if (fr == 0) {
        const float b2v = b2[0];
        float px = 0.f, py = 0.f, pz = 0.f;
#pragma unroll
        for (int i = 0; i < 4; ++i) {
            const int a = a0w + fg * 4 + i;
            const float out = sdip[i] + b2v;
            px += out * tvv[a * 3 + 0];
            py += out * tvv[a * 3 + 1];
            pz += out * tvv[a * 3 + 2];
        }
        sred[wave][fg][0] = px; sred[wave][fg][1] = py; sred[wave][fg][2] = pz;
    }
    __syncthreads();
    if (tid < 3) {
        float s = 0.f;
#pragma unroll
        for (int w = 0; w < 4; ++w)
#pragma unroll
            for (int g = 0; g < 4; ++g) s += sred[w][g][tid];
        unsafeAtomicAdd(&dipole[mol * 3 + tid], s);
    }
}

// ---------------------------------------------------------------------------
extern "C" void kernel_launch(void* const* d_in, const int* in_sizes, int n_in,
                              void* d_out, int out_size, void* d_ws, size_t ws_size,
                              hipStream_t stream)
{
    const float* cart       = (const float*)d_in[0];
    const float* shifts     = (const float*)d_in[1];
    const float* centers    = (const float*)d_in[2];
    const float* widths     = (const float*)d_in[3];
    const float* c_emb      = (const float*)d_in[4];
    const float* W1         = (const float*)d_in[5];
    const float* b1         = (const float*)d_in[6];
    const float* W2         = (const float*)d_in[7];
    const float* b2         = (const float*)d_in[8];
    const int*   species    = (const int*)d_in[10];
    const int*   atom_index = (const int*)d_in[11];

    // ws: cnt(512KB) | soff_g(512KB) | tvv(192KB) | dens_bf(2MB) | rec(17.8MB)
    unsigned*       cnt     = (unsigned*)d_ws;
    unsigned*       soff_g  = cnt + (size_t)TOTNATOM * NSUB;
    float*          tvv     = (float*)(soff_g + (size_t)NMOL * NSUB * NATOM);
    unsigned short* dens_bf = (unsigned short*)(tvv + (size_t)TOTNATOM * 3);
    float4*         rec     = (float4*)(dens_bf + (size_t)TOTNATOM * NB);
    float*          dipole  = (float*)d_out;

    hipLaunchKernelGGL(scatter_kernel, dim3(NMOL * NSUB), dim3(1024), 0, stream,
                       cart, shifts, species, atom_index, cnt, soff_g, rec,
                       dipole, out_size);
    hipLaunchKernelGGL(gather_kernel, dim3(TOTNATOM / ABLK), dim3(256), 0, stream,
                       cnt, soff_g, rec, centers, widths, c_emb, dens_bf, tvv);
    hipLaunchKernelGGL(nn_kernel, dim3(TOTNATOM / 64), dim3(256), 0, stream,
                       dens_bf, tvv, W1, b1, W2, b2, dipole);
}

// Round 28
// 44.607 us; speedup vs baseline: 4.9789x; 1.0330x over previous
//
#include <hip/hip_runtime.h>

#define NMOL   32
#define NATOM  512
#define NPAIR  32768
#define NB     64
#define HIDDEN 256
#define TOTNATOM (NMOL * NATOM)
#define NSUB   8
#define BLKCAP4 4352   // all-valid records/block (exactly 4096 + slack)
#define ABLK   4       // R28: 8->4 atoms/block -> 4096 blocks, ~12.5KB LDS,
                       // 8 blocks/CU (32 waves) vs 8 blocks' worth before
#define NSLOT  128     // per-atom record slots (lambda 64, +8 sigma)
#define CSLOT  64      // per-atom compacted in-cutoff slots (lambda 17, +11 sigma)

typedef __attribute__((ext_vector_type(8))) short bf16x8;
typedef __attribute__((ext_vector_type(4))) float f32x4;

__device__ __forceinline__ unsigned short f2bf(float x) {   // RNE f32->bf16
    unsigned u = __float_as_uint(x);
    u += 0x7FFFu + ((u >> 16) & 1u);
    return (unsigned short)(u >> 16);
}

// ---------------------------------------------------------------------------
// K1 scatter: verbatim R27 (measured-backed: noTV skeleton 3.5us/rep + 16B
// records; only remaining LDS atomic is lcnt).
// ---------------------------------------------------------------------------
__global__ __launch_bounds__(1024) void scatter_kernel(
    const float* __restrict__ cart, const float* __restrict__ shifts,
    const int* __restrict__ species, const int* __restrict__ atom_index,
    unsigned* __restrict__ cnt, unsigned* __restrict__ soff_g,
    float4* __restrict__ rec, float* __restrict__ dipole, int ndip)
{
    __shared__ float    s_cart[NATOM * 3];  // 6 KB
    __shared__ int      s_sp[NATOM];        // 2 KB
    __shared__ unsigned lcnt[NATOM];        // 2 KB
    __shared__ unsigned pref[NATOM];        // 2 KB
    __shared__ unsigned stot;
    __shared__ float4   list[BLKCAP4];      // 68 KB (1 block/CU)

    const int tid  = threadIdx.x;
    const int lane = tid & 63;
    const int wave = tid >> 6;
    const int b    = blockIdx.x;
    const int mol  = b >> 3;
    const int sub  = b & 7;

    if (b == 0 && tid < ndip) dipole[tid] = 0.f;

    const float* cm = cart + (size_t)mol * NATOM * 3;
    const int*   sp = species + (size_t)mol * NATOM;
    for (int i = tid; i < NATOM * 3; i += 1024) s_cart[i] = cm[i];
    if (tid < NATOM) { lcnt[tid] = 0u; s_sp[tid] = sp[tid]; }
    __syncthreads();

    const int* ai0 = atom_index + (size_t)mol * NPAIR;
    const int* ai1 = ai0 + (size_t)NMOL * NPAIR;
    const float* sh = shifts + (size_t)mol * NPAIR * 3;
    const int base = sub * 4096;

    int   gi0[4], gi1[4];
    float gsx[4], gsy[4], gsz[4];
#pragma unroll
    for (int k = 0; k < 4; ++k) {              // batched global loads
        const int p = base + k * 1024 + tid;
        gi0[k] = ai0[p];
        gi1[k] = ai1[p];
        gsx[k] = sh[p * 3 + 0];
        gsy[k] = sh[p * 3 + 1];
        gsz[k] = sh[p * 3 + 2];
    }

    float    rx[4], ry[4], rz[4];
    unsigned rs[4], rp[4];
    int      ri[4];
#pragma unroll
    for (int k = 0; k < 4; ++k) {
        const int a3 = gi0[k] * 3, b3 = gi1[k] * 3;
        const bool m = (gsx[k] > -1e10f && gsy[k] > -1e10f && gsz[k] > -1e10f);
        ri[k] = -1;
        if (m) {                               // masked pairs contribute nothing
            rx[k] = s_cart[a3 + 0] - s_cart[b3 + 0] + gsx[k];
            ry[k] = s_cart[a3 + 1] - s_cart[b3 + 1] + gsy[k];
            rz[k] = s_cart[a3 + 2] - s_cart[b3 + 2] + gsz[k];
            rs[k] = (unsigned)s_sp[gi1[k]];
            ri[k] = gi0[k];
            rp[k] = atomicAdd(&lcnt[gi0[k]], 1u);   // rtn = within-atom ordinal
        }
    }
    __syncthreads();

    if (wave == 0) {                           // single-wave exclusive scan
        unsigned c[8], s = 0;
#pragma unroll
        for (int j = 0; j < 8; ++j) { c[j] = lcnt[lane * 8 + j]; s += c[j]; }
        unsigned incl = s;
#pragma unroll
        for (int off = 1; off < 64; off <<= 1) {
            const unsigned v = __shfl_up(incl, off);
            if (lane >= off) incl += v;
        }
        unsigned run = incl - s;
#pragma unroll
        for (int j = 0; j < 8; ++j) { pref[lane * 8 + j] = run; run += c[j]; }
        if (lane == 63) stot = incl;
    }
    __syncthreads();

#pragma unroll
    for (int k = 0; k < 4; ++k) {              // pass 2: divergent plain writes
        if (ri[k] >= 0) {
            const unsigned idx = pref[ri[k]] + rp[k];
            if (idx < (unsigned)BLKCAP4)
                list[idx] = make_float4(rx[k], ry[k], rz[k], __uint_as_float(rs[k]));
        }
    }
    __syncthreads();

    const int tot = min((int)stot, BLKCAP4);   // coalesced sweep
    float4* dstr = rec + (size_t)b * BLKCAP4;
    for (int i = tid; i < tot; i += 1024) dstr[i] = list[i];

    if (tid < NATOM) {
        cnt[((size_t)mol * NATOM + tid) * NSUB + sub] = lcnt[tid];
        soff_g[(size_t)b * NATOM + tid] = pref[tid];
    }
}

// ---------------------------------------------------------------------------
// K2 gather: R28 regrid. 4096 blocks x 256 thr, 4 atoms/block (~12.5KB LDS ->
// 8 blocks/CU, 4x TLP of R27). Segment copy: 8 threads/segment -> 8x16B=128B
// contiguous per segment (fully coalesced, vs R27's stride-4 pattern).
// Wave = 1 atom; phase A usually a single 64-lane pass.
// ---------------------------------------------------------------------------
__global__ __launch_bounds__(256) void gather_kernel(
    const unsigned* __restrict__ cnt, const unsigned* __restrict__ soff_g,
    const float4* __restrict__ rec,
    const float* __restrict__ centers, const float* __restrict__ widths,
    const float* __restrict__ c_emb,
    unsigned short* __restrict__ dens_bf, float* __restrict__ tvv)
{
    __shared__ float    cemb[8 * NB];          // 2 KB
    __shared__ float4   list4[ABLK][NSLOT];    // 8 KB
    __shared__ float2   cbuf[ABLK][CSLOT];     // 2 KB
    __shared__ unsigned scnt[ABLK][NSUB];
    __shared__ unsigned sofg[ABLK][NSUB];
    __shared__ unsigned soff[ABLK][NSUB];
    __shared__ unsigned ntot[ABLK];

    const int tid = threadIdx.x;
    const int a0  = blockIdx.x * ABLK;
    const int mol = a0 >> 9;
    const int ra0 = a0 & 511;

    for (int i = tid; i < 8 * NB; i += 256) cemb[i] = c_emb[i];
    if (tid < ABLK * NSUB) {                   // 32 loads
        const int al = tid >> 3, s = tid & 7;
        scnt[al][s] = cnt[(size_t)(a0 + al) * NSUB + s];
        sofg[al][s] = soff_g[(size_t)(mol * NSUB + s) * NATOM + (ra0 + al)];
    }
    __syncthreads();

    if (tid < ABLK) {                          // per-atom prefix over 8 segs
        int o = 0;
#pragma unroll
        for (int s = 0; s < NSUB; ++s) {
            soff[tid][s] = (unsigned)o;
            o += min((int)scnt[tid][s], NSLOT - o);
        }
        ntot[tid] = (unsigned)o;               // exact count (<=128)
    }
    __syncthreads();

    {   // segment copy: 8 threads per (atom, sub) segment (32 segments)
        const int seg = tid >> 3;              // 0..31
        const int prt = tid & 7;
        const int al = seg >> 3, s = seg & 7;
        const int off = (int)soff[al][s];
        const int n = min((int)scnt[al][s], NSLOT - off);
        const float4* src = rec + (size_t)(mol * NSUB + s) * BLKCAP4 + sofg[al][s];
        float4* dst = &list4[al][off];
        for (int k = prt; k < n; k += 8) dst[k] = src[k];
    }
    __syncthreads();

    const int lane = tid & 63;
    const int al   = tid >> 6;                 // wave = atom (4 waves, 4 atoms)
    const int a    = a0 + al;

    const float L2E = 1.4426950408889634f;
    const float wl  = widths[lane];
    const float cl  = centers[lane];
    const float qe  = -wl * L2E;
    const float qb  = 2.f * wl * cl * L2E;
    const float qa  = -wl * cl * cl * L2E;

    // ---- phase A: lane = record ----
    const int n = (int)ntot[al];
    float tx = 0.f, ty = 0.f, tz = 0.f;
    int mbase = 0;
    for (int c0 = 0; c0 < n; c0 += 64) {
        const int k = c0 + lane;
        const bool valid = (k < n);
        float4 q = make_float4(0.f, 0.f, 0.f, 0.f);
        if (valid) q = list4[al][k];
        tx += q.x; ty += q.y; tz += q.z;
        const float d = sqrtf(q.x * q.x + q.y * q.y + q.z * q.z + 1e-12f);
        const bool in = valid && (d < 5.0f);
        const unsigned long long mask = __ballot(in);
        if (in) {
            const float fc = 0.5f * (__cosf(0.62831853071795864769f * d) + 1.f);
            const unsigned fb = (__float_as_uint(fc) & ~7u)
                              | (__float_as_uint(q.w) & 7u);
            const int pos = __builtin_amdgcn_mbcnt_hi((unsigned)(mask >> 32),
                          __builtin_amdgcn_mbcnt_lo((unsigned)mask, 0u));
            const int idx = mbase + pos;
            if (idx < CSLOT) cbuf[al][idx] = make_float2(d, __uint_as_float(fb));
        }
        mbase += (int)__popcll(mask);
    }
    if (mbase > CSLOT) mbase = CSLOT;
    const int mp = (mbase + 7) & ~7;           // pad to multiple of 8
    if (lane < mp - mbase) cbuf[al][mbase + lane] = make_float2(0.f, 0.f);
#pragma unroll
    for (int off = 32; off; off >>= 1) {       // tv shuffle reduce
        tx += __shfl_down(tx, off);
        ty += __shfl_down(ty, off);
        tz += __shfl_down(tz, off);
    }
    if (lane == 0) {
        tvv[(size_t)a * 3 + 0] = tx;
        tvv[(size_t)a * 3 + 1] = ty;
        tvv[(size_t)a * 3 + 2] = tz;
    }
    // (same wave wrote cbuf; compiler inserts lgkmcnt -- no barrier needed)

    // ---- phase B: lane = basis ----
#define REC1(A, dv, fv) { const unsigned f_ = __float_as_uint(fv);           \
        const float v_ = fmaf(dv, fmaf(dv, qe, qb), qa);                     \
        A = fmaf(exp2f(v_) * __uint_as_float(f_ & ~7u),                      \
                 cemb[((f_ & 7u) << 6) | lane], A); }
    const float4* l4 = reinterpret_cast<const float4*>(cbuf[al]);
    float acc0 = 0.f, acc1 = 0.f;
    for (int j = 0; j < mp; j += 8) {
        const float4 q0 = l4[(j >> 1) + 0];
        const float4 q1 = l4[(j >> 1) + 1];
        const float4 q2 = l4[(j >> 1) + 2];
        const float4 q3 = l4[(j >> 1) + 3];
        REC1(acc0, q0.x, q0.y) REC1(acc1, q0.z, q0.w)
        REC1(acc0, q1.x, q1.y) REC1(acc1, q1.z, q1.w)
        REC1(acc0, q2.x, q2.y) REC1(acc1, q2.z, q2.w)
        REC1(acc0, q3.x, q3.y) REC1(acc1, q3.z, q3.w)
    }
#undef REC1
    dens_bf[(size_t)a * NB + lane] = f2bf(acc0 + acc1);
}

// ---------------------------------------------------------------------------
// K3 nn via MFMA: verbatim R27.
// ---------------------------------------------------------------------------
__global__ __launch_bounds__(256) void nn_kernel(
    const unsigned short* __restrict__ dens_bf, const float* __restrict__ tvv,
    const float* __restrict__ W1, const float* __restrict__ b1,
    const float* __restrict__ W2, const float* __restrict__ b2,
    float* __restrict__ dipole)
{
    __shared__ __align__(16) unsigned short w1t[HIDDEN * 72];
    __shared__ float b1_l[HIDDEN], w2_l[HIDDEN];
    __shared__ float sred[4][4][3];

    const int tid = threadIdx.x;
    const int mol = blockIdx.x >> 3;

    for (int i = tid; i < NB * HIDDEN; i += 256) {
        const int k = i >> 8, j = i & 255;
        w1t[j * 72 + k] = f2bf(W1[i]);
    }
    if (tid < HIDDEN) { b1_l[tid] = b1[tid]; w2_l[tid] = W2[tid]; }
    __syncthreads();

    const int lane = tid & 63;
    const int wave = tid >> 6;
    const int fr   = lane & 15;
    const int fg   = lane >> 4;
    const int a0w  = blockIdx.x * 64 + wave * 16;

    bf16x8 afr[2];
#pragma unroll
    for (int kk = 0; kk < 2; ++kk)
        afr[kk] = *reinterpret_cast<const bf16x8*>(
            dens_bf + (size_t)(a0w + fr) * NB + kk * 32 + fg * 8);

    float sdip[4] = {0.f, 0.f, 0.f, 0.f};
#pragma unroll
    for (int nt = 0; nt < 16; ++nt) {
        const bf16x8 bf0 = *reinterpret_cast<const bf16x8*>(
            &w1t[(nt * 16 + fr) * 72 + 0 + fg * 8]);
        const bf16x8 bf1 = *reinterpret_cast<const bf16x8*>(
            &w1t[(nt * 16 + fr) * 72 + 32 + fg * 8]);
        f32x4 acc = {0.f, 0.f, 0.f, 0.f};
        acc = __builtin_amdgcn_mfma_f32_16x16x32_bf16(afr[0], bf0, acc, 0, 0, 0);
        acc = __builtin_amdgcn_mfma_f32_16x16x32_bf16(afr[1], bf1, acc, 0, 0, 0);
        const int j = nt * 16 + fr;
        const float b1v = b1_l[j], w2v = w2_l[j];
#pragma unroll
        for (int i = 0; i < 4; ++i) {
            const float h = acc[i] + b1v;
            sdip[i] += (h / (1.f + __expf(-h))) * w2v;
        }
    }
#pragma unroll
    for (int off = 1; off < 16; off <<= 1) {
#pragma unroll
        for (int i = 0; i < 4; ++i) sdip[i] += __shfl_xor(sdip[i], off);
    }
    if (fr == 0) {
        const float b2v = b2[0];
        float px = 0.f, py = 0.f, pz = 0.f;
#pragma unroll
        for (int i = 0; i < 4; ++i) {
            const int a = a0w + fg * 4 + i;
            const float out = sdip[i] + b2v;
            px += out * tvv[a * 3 + 0];
            py += out * tvv[a * 3 + 1];
            pz += out * tvv[a * 3 + 2];
        }
        sred[wave][fg][0] = px; sred[wave][fg][1] = py; sred[wave][fg][2] = pz;
    }
    __syncthreads();
    if (tid < 3) {
        float s = 0.f;
#pragma unroll
        for (int w = 0; w < 4; ++w)
#pragma unroll
            for (int g = 0; g < 4; ++g) s += sred[w][g][tid];
        unsafeAtomicAdd(&dipole[mol * 3 + tid], s);
    }
}

// ---------------------------------------------------------------------------
extern "C" void kernel_launch(void* const* d_in, const int* in_sizes, int n_in,
                              void* d_out, int out_size, void* d_ws, size_t ws_size,
                              hipStream_t stream)
{
    const float* cart       = (const float*)d_in[0];
    const float* shifts     = (const float*)d_in[1];
    const float* centers    = (const float*)d_in[2];
    const float* widths     = (const float*)d_in[3];
    const float* c_emb      = (const float*)d_in[4];
    const float* W1         = (const float*)d_in[5];
    const float* b1         = (const float*)d_in[6];
    const float* W2         = (const float*)d_in[7];
    const float* b2         = (const float*)d_in[8];
    const int*   species    = (const int*)d_in[10];
    const int*   atom_index = (const int*)d_in[11];

    // ws: cnt(512KB) | soff_g(512KB) | tvv(192KB) | dens_bf(2MB) | rec(17.8MB)
    unsigned*       cnt     = (unsigned*)d_ws;
    unsigned*       soff_g  = cnt + (size_t)TOTNATOM * NSUB;
    float*          tvv     = (float*)(soff_g + (size_t)NMOL * NSUB * NATOM);
    unsigned short* dens_bf = (unsigned short*)(tvv + (size_t)TOTNATOM * 3);
    float4*         rec     = (float4*)(dens_bf + (size_t)TOTNATOM * NB);
    float*          dipole  = (float*)d_out;

    hipLaunchKernelGGL(scatter_kernel, dim3(NMOL * NSUB), dim3(1024), 0, stream,
                       cart, shifts, species, atom_index, cnt, soff_g, rec,
                       dipole, out_size);
    hipLaunchKernelGGL(gather_kernel, dim3(TOTNATOM / ABLK), dim3(256), 0, stream,
                       cnt, soff_g, rec, centers, widths, c_emb, dens_bf, tvv);
    hipLaunchKernelGGL(nn_kernel, dim3(TOTNATOM / 64), dim3(256), 0, stream,
                       dens_bf, tvv, W1, b1, W2, b2, dipole);
}

// Round 29
// 42.316 us; speedup vs baseline: 5.2485x; 1.0541x over previous
//
#include <hip/hip_runtime.h>

#define NMOL   32
#define NATOM  512
#define NPAIR  32768
#define NB     64
#define HIDDEN 256
#define TOTNATOM (NMOL * NATOM)
#define NSUB   8
#define BLKCAP4 4352   // all-valid records/block (exactly 4096 + slack)
#define ABLK   4
#define NSLOT  128     // per-atom record slots (lambda 64, +8 sigma)
#define CSLOT  64      // per-atom compacted in-cutoff slots

typedef __attribute__((ext_vector_type(8))) short bf16x8;
typedef __attribute__((ext_vector_type(4))) float f32x4;

__device__ __forceinline__ unsigned short f2bf(float x) {   // RNE f32->bf16
    unsigned u = __float_as_uint(x);
    u += 0x7FFFu + ((u >> 16) & 1u);
    return (unsigned short)(u >> 16);
}

// ---------------------------------------------------------------------------
// K1 scatter: verbatim R28 EXCEPT the block->(mol,sub) map: mol = b&31,
// sub = b>>5. With XCD = blockIdx%8 (round-robin heuristic), b === mol (mod 32)
// => all 8 sub-blocks of molecule m run on XCD m%8, so mol m's rec/cnt stay
// in ONE XCD's L2 for the consumer kernels (R29 cross-XCD-locality theory).
// ---------------------------------------------------------------------------
__global__ __launch_bounds__(1024) void scatter_kernel(
    const float* __restrict__ cart, const float* __restrict__ shifts,
    const int* __restrict__ species, const int* __restrict__ atom_index,
    unsigned* __restrict__ cnt, unsigned* __restrict__ soff_g,
    float4* __restrict__ rec, float* __restrict__ dipole, int ndip)
{
    __shared__ float    s_cart[NATOM * 3];  // 6 KB
    __shared__ int      s_sp[NATOM];        // 2 KB
    __shared__ unsigned lcnt[NATOM];        // 2 KB
    __shared__ unsigned pref[NATOM];        // 2 KB
    __shared__ unsigned stot;
    __shared__ float4   list[BLKCAP4];      // 68 KB (1 block/CU)

    const int tid  = threadIdx.x;
    const int lane = tid & 63;
    const int wave = tid >> 6;
    const int b    = blockIdx.x;
    const int mol  = b & 31;               // R29 swizzle (was b>>3)
    const int sub  = b >> 5;               // R29 swizzle (was b&7)

    if (b == 0 && tid < ndip) dipole[tid] = 0.f;

    const float* cm = cart + (size_t)mol * NATOM * 3;
    const int*   sp = species + (size_t)mol * NATOM;
    for (int i = tid; i < NATOM * 3; i += 1024) s_cart[i] = cm[i];
    if (tid < NATOM) { lcnt[tid] = 0u; s_sp[tid] = sp[tid]; }
    __syncthreads();

    const int* ai0 = atom_index + (size_t)mol * NPAIR;
    const int* ai1 = ai0 + (size_t)NMOL * NPAIR;
    const float* sh = shifts + (size_t)mol * NPAIR * 3;
    const int base = sub * 4096;

    int   gi0[4], gi1[4];
    float gsx[4], gsy[4], gsz[4];
#pragma unroll
    for (int k = 0; k < 4; ++k) {              // batched global loads
        const int p = base + k * 1024 + tid;
        gi0[k] = ai0[p];
        gi1[k] = ai1[p];
        gsx[k] = sh[p * 3 + 0];
        gsy[k] = sh[p * 3 + 1];
        gsz[k] = sh[p * 3 + 2];
    }

    float    rx[4], ry[4], rz[4];
    unsigned rs[4], rp[4];
    int      ri[4];
#pragma unroll
    for (int k = 0; k < 4; ++k) {
        const int a3 = gi0[k] * 3, b3 = gi1[k] * 3;
        const bool m = (gsx[k] > -1e10f && gsy[k] > -1e10f && gsz[k] > -1e10f);
        ri[k] = -1;
        if (m) {                               // masked pairs contribute nothing
            rx[k] = s_cart[a3 + 0] - s_cart[b3 + 0] + gsx[k];
            ry[k] = s_cart[a3 + 1] - s_cart[b3 + 1] + gsy[k];
            rz[k] = s_cart[a3 + 2] - s_cart[b3 + 2] + gsz[k];
            rs[k] = (unsigned)s_sp[gi1[k]];
            ri[k] = gi0[k];
            rp[k] = atomicAdd(&lcnt[gi0[k]], 1u);   // rtn = within-atom ordinal
        }
    }
    __syncthreads();

    if (wave == 0) {                           // single-wave exclusive scan
        unsigned c[8], s = 0;
#pragma unroll
        for (int j = 0; j < 8; ++j) { c[j] = lcnt[lane * 8 + j]; s += c[j]; }
        unsigned incl = s;
#pragma unroll
        for (int off = 1; off < 64; off <<= 1) {
            const unsigned v = __shfl_up(incl, off);
            if (lane >= off) incl += v;
        }
        unsigned run = incl - s;
#pragma unroll
        for (int j = 0; j < 8; ++j) { pref[lane * 8 + j] = run; run += c[j]; }
        if (lane == 63) stot = incl;
    }
    __syncthreads();

#pragma unroll
    for (int k = 0; k < 4; ++k) {              // pass 2: divergent plain writes
        if (ri[k] >= 0) {
            const unsigned idx = pref[ri[k]] + rp[k];
            if (idx < (unsigned)BLKCAP4)
                list[idx] = make_float4(rx[k], ry[k], rz[k], __uint_as_float(rs[k]));
        }
    }
    __syncthreads();

    const int tot = min((int)stot, BLKCAP4);   // coalesced sweep
    float4* dstr = rec + (size_t)b * BLKCAP4;
    for (int i = tid; i < tot; i += 1024) dstr[i] = list[i];

    if (tid < NATOM) {
        cnt[((size_t)mol * NATOM + tid) * NSUB + sub] = lcnt[tid];
        soff_g[(size_t)b * NATOM + tid] = pref[tid];
    }
}

// ---------------------------------------------------------------------------
// K2 gather: verbatim R28 except block->mol map: mol = B&31, inner = B>>5
// (same-XCD as mol's scatter blocks => rec/cnt reads are home-L2 hits).
// ---------------------------------------------------------------------------
__global__ __launch_bounds__(256) void gather_kernel(
    const unsigned* __restrict__ cnt, const unsigned* __restrict__ soff_g,
    const float4* __restrict__ rec,
    const float* __restrict__ centers, const float* __restrict__ widths,
    const float* __restrict__ c_emb,
    unsigned short* __restrict__ dens_bf, float* __restrict__ tvv)
{
    __shared__ float    cemb[8 * NB];          // 2 KB
    __shared__ float4   list4[ABLK][NSLOT];    // 8 KB
    __shared__ float2   cbuf[ABLK][CSLOT];     // 2 KB
    __shared__ unsigned scnt[ABLK][NSUB];
    __shared__ unsigned sofg[ABLK][NSUB];
    __shared__ unsigned soff[ABLK][NSUB];
    __shared__ unsigned ntot[ABLK];

    const int tid   = threadIdx.x;
    const int B     = blockIdx.x;
    const int mol   = B & 31;                  // R29 swizzle
    const int inner = B >> 5;                  // 0..127
    const int a0    = mol * NATOM + inner * ABLK;
    const int ra0   = inner * ABLK;

    for (int i = tid; i < 8 * NB; i += 256) cemb[i] = c_emb[i];
    if (tid < ABLK * NSUB) {                   // 32 loads
        const int al = tid >> 3, s = tid & 7;
        scnt[al][s] = cnt[(size_t)(a0 + al) * NSUB + s];
        sofg[al][s] = soff_g[(size_t)(s * NMOL + mol) * NATOM + (ra0 + al)];
    }
    __syncthreads();

    if (tid < ABLK) {                          // per-atom prefix over 8 segs
        int o = 0;
#pragma unroll
        for (int s = 0; s < NSUB; ++s) {
            soff[tid][s] = (unsigned)o;
            o += min((int)scnt[tid][s], NSLOT - o);
        }
        ntot[tid] = (unsigned)o;               // exact count (<=128)
    }
    __syncthreads();

    {   // segment copy: 8 threads per (atom, sub) segment (32 segments)
        const int seg = tid >> 3;              // 0..31
        const int prt = tid & 7;
        const int al = seg >> 3, s = seg & 7;
        const int off = (int)soff[al][s];
        const int n = min((int)scnt[al][s], NSLOT - off);
        const float4* src = rec + (size_t)(s * NMOL + mol) * BLKCAP4 + sofg[al][s];
        float4* dst = &list4[al][off];
        for (int k = prt; k < n; k += 8) dst[k] = src[k];
    }
    __syncthreads();

    const int lane = tid & 63;
    const int al   = tid >> 6;                 // wave = atom (4 waves, 4 atoms)
    const int a    = a0 + al;

    const float L2E = 1.4426950408889634f;
    const float wl  = widths[lane];
    const float cl  = centers[lane];
    const float qe  = -wl * L2E;
    const float qb  = 2.f * wl * cl * L2E;
    const float qa  = -wl * cl * cl * L2E;

    // ---- phase A: lane = record ----
    const int n = (int)ntot[al];
    float tx = 0.f, ty = 0.f, tz = 0.f;
    int mbase = 0;
    for (int c0 = 0; c0 < n; c0 += 64) {
        const int k = c0 + lane;
        const bool valid = (k < n);
        float4 q = make_float4(0.f, 0.f, 0.f, 0.f);
        if (valid) q = list4[al][k];
        tx += q.x; ty += q.y; tz += q.z;
        const float d = sqrtf(q.x * q.x + q.y * q.y + q.z * q.z + 1e-12f);
        const bool in = valid && (d < 5.0f);
        const unsigned long long mask = __ballot(in);
        if (in) {
            const float fc = 0.5f * (__cosf(0.62831853071795864769f * d) + 1.f);
            const unsigned fb = (__float_as_uint(fc) & ~7u)
                              | (__float_as_uint(q.w) & 7u);
            const int pos = __builtin_amdgcn_mbcnt_hi((unsigned)(mask >> 32),
                          __builtin_amdgcn_mbcnt_lo((unsigned)mask, 0u));
            const int idx = mbase + pos;
            if (idx < CSLOT) cbuf[al][idx] = make_float2(d, __uint_as_float(fb));
        }
        mbase += (int)__popcll(mask);
    }
    if (mbase > CSLOT) mbase = CSLOT;
    const int mp = (mbase + 7) & ~7;           // pad to multiple of 8
    if (lane < mp - mbase) cbuf[al][mbase + lane] = make_float2(0.f, 0.f);
#pragma unroll
    for (int off = 32; off; off >>= 1) {       // tv shuffle reduce
        tx += __shfl_down(tx, off);
        ty += __shfl_down(ty, off);
        tz += __shfl_down(tz, off);
    }
    if (lane == 0) {
        tvv[(size_t)a * 3 + 0] = tx;
        tvv[(size_t)a * 3 + 1] = ty;
        tvv[(size_t)a * 3 + 2] = tz;
    }
    // (same wave wrote cbuf; compiler inserts lgkmcnt -- no barrier needed)

    // ---- phase B: lane = basis ----
#define REC1(A, dv, fv) { const unsigned f_ = __float_as_uint(fv);           \
        const float v_ = fmaf(dv, fmaf(dv, qe, qb), qa);                     \
        A = fmaf(exp2f(v_) * __uint_as_float(f_ & ~7u),                      \
                 cemb[((f_ & 7u) << 6) | lane], A); }
    const float4* l4 = reinterpret_cast<const float4*>(cbuf[al]);
    float acc0 = 0.f, acc1 = 0.f;
    for (int j = 0; j < mp; j += 8) {
        const float4 q0 = l4[(j >> 1) + 0];
        const float4 q1 = l4[(j >> 1) + 1];
        const float4 q2 = l4[(j >> 1) + 2];
        const float4 q3 = l4[(j >> 1) + 3];
        REC1(acc0, q0.x, q0.y) REC1(acc1, q0.z, q0.w)
        REC1(acc0, q1.x, q1.y) REC1(acc1, q1.z, q1.w)
        REC1(acc0, q2.x, q2.y) REC1(acc1, q2.z, q2.w)
        REC1(acc0, q3.x, q3.y) REC1(acc1, q3.z, q3.w)
    }
#undef REC1
    dens_bf[(size_t)a * NB + lane] = f2bf(acc0 + acc1);
}

// ---------------------------------------------------------------------------
// K3 nn via MFMA: verbatim R28 except block->mol map: mol = B&31,
// chunk = B>>5 (same-XCD as mol's gather blocks => dens_bf reads home-L2).
// ---------------------------------------------------------------------------
__global__ __launch_bounds__(256) void nn_kernel(
    const unsigned short* __restrict__ dens_bf, const float* __restrict__ tvv,
    const float* __restrict__ W1, const float* __restrict__ b1,
    const float* __restrict__ W2, const float* __restrict__ b2,
    float* __restrict__ dipole)
{
    __shared__ __align__(16) unsigned short w1t[HIDDEN * 72];
    __shared__ float b1_l[HIDDEN], w2_l[HIDDEN];
    __shared__ float sred[4][4][3];

    const int tid   = threadIdx.x;
    const int B     = blockIdx.x;
    const int mol   = B & 31;                  // R29 swizzle
    const int chunk = B >> 5;                  // 0..7

    for (int i = tid; i < NB * HIDDEN; i += 256) {
        const int k = i >> 8, j = i & 255;
        w1t[j * 72 + k] = f2bf(W1[i]);
    }
    if (tid < HIDDEN) { b1_l[tid] = b1[tid]; w2_l[tid] = W2[tid]; }
    __syncthreads();

    const int lane = tid & 63;
    const int wave = tid >> 6;
    const int fr   = lane & 15;
    const int fg   = lane >> 4;
    const int a0w  = mol * NATOM + chunk * 64 + wave * 16;

    bf16x8 afr[2];
#pragma unroll
    for (int kk = 0; kk < 2; ++kk)
        afr[kk] = *reinterpret_cast<const bf16x8*>(
            dens_bf + (size_t)(a0w + fr) * NB + kk * 32 + fg * 8);

    float sdip[4] = {0.f, 0.f, 0.f, 0.f};
#pragma unroll
    for (int nt = 0; nt < 16; ++nt) {
        const bf16x8 bf0 = *reinterpret_cast<const bf16x8*>(
            &w1t[(nt * 16 + fr) * 72 + 0 + fg * 8]);
        const bf16x8 bf1 = *reinterpret_cast<const bf16x8*>(
            &w1t[(nt * 16 + fr) * 72 + 32 + fg * 8]);
        f32x4 acc = {0.f, 0.f, 0.f, 0.f};
        acc = __builtin_amdgcn_mfma_f32_16x16x32_bf16(afr[0], bf0, acc, 0, 0, 0);
        acc = __builtin_amdgcn_mfma_f32_16x16x32_bf16(afr[1], bf1, acc, 0, 0, 0);
        const int j = nt * 16 + fr;
        const float b1v = b1_l[j], w2v = w2_l[j];
#pragma unroll
        for (int i = 0; i < 4; ++i) {
            const float h = acc[i] + b1v;
            sdip[i] += (h / (1.f + __expf(-h))) * w2v;
        }
    }
#pragma unroll
    for (int off = 1; off < 16; off <<= 1) {
#pragma unroll
        for (int i = 0; i < 4; ++i) sdip[i] += __shfl_xor(sdip[i], off);
    }
    if (fr == 0) {
        const float b2v = b2[0];
        float px = 0.f, py = 0.f, pz = 0.f;
#pragma unroll
        for (int i = 0; i < 4; ++i) {
            const int a = a0w + fg * 4 + i;
            const float out = sdip[i] + b2v;
            px += out * tvv[a * 3 + 0];
            py += out * tvv[a * 3 + 1];
            pz += out * tvv[a * 3 + 2];
        }
        sred[wave][fg][0] = px; sred[wave][fg][1] = py; sred[wave][fg][2] = pz;
    }
    __syncthreads();
    if (tid < 3) {
        float s = 0.f;
#pragma unroll
        for (int w = 0; w < 4; ++w)
#pragma unroll
            for (int g = 0; g < 4; ++g) s += sred[w][g][tid];
        unsafeAtomicAdd(&dipole[mol * 3 + tid], s);
    }
}

// ---------------------------------------------------------------------------
extern "C" void kernel_launch(void* const* d_in, const int* in_sizes, int n_in,
                              void* d_out, int out_size, void* d_ws, size_t ws_size,
                              hipStream_t stream)
{
    const float* cart       = (const float*)d_in[0];
    const float* shifts     = (const float*)d_in[1];
    const float* centers    = (const float*)d_in[2];
    const float* widths     = (const float*)d_in[3];
    const float* c_emb      = (const float*)d_in[4];
    const float* W1         = (const float*)d_in[5];
    const float* b1         = (const float*)d_in[6];
    const float* W2         = (const float*)d_in[7];
    const float* b2         = (const float*)d_in[8];
    const int*   species    = (const int*)d_in[10];
    const int*   atom_index = (const int*)d_in[11];

    // ws: cnt(512KB) | soff_g(512KB) | tvv(192KB) | dens_bf(2MB) | rec(17.8MB)
    unsigned*       cnt     = (unsigned*)d_ws;
    unsigned*       soff_g  = cnt + (size_t)TOTNATOM * NSUB;
    float*          tvv     = (float*)(soff_g + (size_t)NMOL * NSUB * NATOM);
    unsigned short* dens_bf = (unsigned short*)(tvv + (size_t)TOTNATOM * 3);
    float4*         rec     = (float4*)(dens_bf + (size_t)TOTNATOM * NB);
    float*          dipole  = (float*)d_out;

    hipLaunchKernelGGL(scatter_kernel, dim3(NMOL * NSUB), dim3(1024), 0, stream,
                       cart, shifts, species, atom_index, cnt, soff_g, rec,
                       dipole, out_size);
    hipLaunchKernelGGL(gather_kernel, dim3(TOTNATOM / ABLK), dim3(256), 0, stream,
                       cnt, soff_g, rec, centers, widths, c_emb, dens_bf, tvv);
    hipLaunchKernelGGL(nn_kernel, dim3(TOTNATOM / 64), dim3(256), 0, stream,
                       dens_bf, tvv, W1, b1, W2, b2, dipole);
}

// Round 30
// 40.725 us; speedup vs baseline: 5.4535x; 1.0391x over previous
//
#include <hip/hip_runtime.h>

#define NMOL   32
#define NATOM  512
#define NPAIR  32768
#define NB     64
#define HIDDEN 256
#define TOTNATOM (NMOL * NATOM)
#define NSUB   8
#define BLKCAP4 4352   // all-valid 16B records/block (4096 + slack), LDS only
#define BLKCAP2 2816   // compacted 8B records/block (lambda ~1065, huge slack)
#define ABLK   4
#define NSLOT  48      // per-atom compacted slots in gather (lambda 17, +7 sigma)

typedef __attribute__((ext_vector_type(8))) short bf16x8;
typedef __attribute__((ext_vector_type(4))) float f32x4;

__device__ __forceinline__ unsigned short f2bf(float x) {   // RNE f32->bf16
    unsigned u = __float_as_uint(x);
    u += 0x7FFFu + ((u >> 16) & 1u);
    return (unsigned short)(u >> 16);
}

// ---------------------------------------------------------------------------
// K1 scatter: R30 -- gather's phase A moved here (records are already
// grouped per-atom in LDS; R26 proved LDS *atomics* were the poison, not
// LDS passes). After pass-2 grouping:
//   walk1 (thread=atom, serial, atomic-free): tv segment-sum -> tv_part,
//          in-cutoff count -> ccnt
//   scan ccnt -> pref2; walk2: emit compacted 8B {d, fc|spc} records
// Output rec is 2.3MB (was 16.8MB); gather loses phase A entirely.
// ---------------------------------------------------------------------------
__global__ __launch_bounds__(1024) void scatter_kernel(
    const float* __restrict__ cart, const float* __restrict__ shifts,
    const int* __restrict__ species, const int* __restrict__ atom_index,
    unsigned* __restrict__ cnt, unsigned* __restrict__ soff_g,
    float2* __restrict__ rec, float* __restrict__ tv_part,
    float* __restrict__ dipole, int ndip)
{
    __shared__ float    s_cart[NATOM * 3];  // 6 KB
    __shared__ int      s_sp[NATOM];        // 2 KB
    __shared__ unsigned lcnt[NATOM];        // 2 KB (all-valid counts)
    __shared__ unsigned pref[NATOM];        // 2 KB
    __shared__ unsigned ccnt[NATOM];        // 2 KB (in-cutoff counts)
    __shared__ unsigned pref2[NATOM];       // 2 KB
    __shared__ unsigned stot2;
    __shared__ float4   list[BLKCAP4];      // 68 KB (all-valid, grouped)
    __shared__ float2   out2[BLKCAP2];      // 22 KB (compacted in-cutoff)

    const int tid  = threadIdx.x;
    const int lane = tid & 63;
    const int wave = tid >> 6;
    const int b    = blockIdx.x;
    const int mol  = b & 31;               // XCD swizzle (R29)
    const int sub  = b >> 5;

    if (b == 0 && tid < ndip) dipole[tid] = 0.f;

    const float* cm = cart + (size_t)mol * NATOM * 3;
    const int*   sp = species + (size_t)mol * NATOM;
    for (int i = tid; i < NATOM * 3; i += 1024) s_cart[i] = cm[i];
    if (tid < NATOM) { lcnt[tid] = 0u; s_sp[tid] = sp[tid]; }
    __syncthreads();

    const int* ai0 = atom_index + (size_t)mol * NPAIR;
    const int* ai1 = ai0 + (size_t)NMOL * NPAIR;
    const float* sh = shifts + (size_t)mol * NPAIR * 3;
    const int base = sub * 4096;

    int   gi0[4], gi1[4];
    float gsx[4], gsy[4], gsz[4];
#pragma unroll
    for (int k = 0; k < 4; ++k) {              // batched global loads
        const int p = base + k * 1024 + tid;
        gi0[k] = ai0[p];
        gi1[k] = ai1[p];
        gsx[k] = sh[p * 3 + 0];
        gsy[k] = sh[p * 3 + 1];
        gsz[k] = sh[p * 3 + 2];
    }

    float    rx[4], ry[4], rz[4];
    unsigned rs[4], rp[4];
    int      ri[4];
#pragma unroll
    for (int k = 0; k < 4; ++k) {
        const int a3 = gi0[k] * 3, b3 = gi1[k] * 3;
        const bool m = (gsx[k] > -1e10f && gsy[k] > -1e10f && gsz[k] > -1e10f);
        ri[k] = -1;
        if (m) {                               // masked pairs contribute nothing
            rx[k] = s_cart[a3 + 0] - s_cart[b3 + 0] + gsx[k];
            ry[k] = s_cart[a3 + 1] - s_cart[b3 + 1] + gsy[k];
            rz[k] = s_cart[a3 + 2] - s_cart[b3 + 2] + gsz[k];
            rs[k] = (unsigned)s_sp[gi1[k]];
            ri[k] = gi0[k];
            rp[k] = atomicAdd(&lcnt[gi0[k]], 1u);   // rtn = within-atom ordinal
        }
    }
    __syncthreads();

    if (wave == 0) {                           // scan lcnt -> pref (exclusive)
        unsigned c[8], s = 0;
#pragma unroll
        for (int j = 0; j < 8; ++j) { c[j] = lcnt[lane * 8 + j]; s += c[j]; }
        unsigned incl = s;
#pragma unroll
        for (int off = 1; off < 64; off <<= 1) {
            const unsigned v = __shfl_up(incl, off);
            if (lane >= off) incl += v;
        }
        unsigned run = incl - s;
#pragma unroll
        for (int j = 0; j < 8; ++j) { pref[lane * 8 + j] = run; run += c[j]; }
    }
    __syncthreads();

#pragma unroll
    for (int k = 0; k < 4; ++k) {              // pass 2: group all-valid 16B
        if (ri[k] >= 0) {
            const unsigned idx = pref[ri[k]] + rp[k];
            if (idx < (unsigned)BLKCAP4)
                list[idx] = make_float4(rx[k], ry[k], rz[k], __uint_as_float(rs[k]));
        }
    }
    __syncthreads();

    // walk1: thread = atom; tv segment-sum + in-cutoff count (atomic-free)
    if (tid < NATOM) {
        const int a  = tid;
        const int j0 = (int)pref[a];
        const int j1 = min(j0 + (int)lcnt[a], BLKCAP4);
        float tx = 0.f, ty = 0.f, tz = 0.f;
        unsigned c2 = 0;
        for (int j = j0; j < j1; ++j) {
            const float4 q = list[j];
            tx += q.x; ty += q.y; tz += q.z;
            const float d = sqrtf(q.x * q.x + q.y * q.y + q.z * q.z + 1e-12f);
            if (d < 5.0f) ++c2;
        }
        ccnt[a] = c2;
        float* tg = tv_part + ((size_t)b * NATOM + a) * 3;
        tg[0] = tx; tg[1] = ty; tg[2] = tz;
    }
    __syncthreads();

    if (wave == 0) {                           // scan ccnt -> pref2
        unsigned c[8], s = 0;
#pragma unroll
        for (int j = 0; j < 8; ++j) { c[j] = ccnt[lane * 8 + j]; s += c[j]; }
        unsigned incl = s;
#pragma unroll
        for (int off = 1; off < 64; off <<= 1) {
            const unsigned v = __shfl_up(incl, off);
            if (lane >= off) incl += v;
        }
        unsigned run = incl - s;
#pragma unroll
        for (int j = 0; j < 8; ++j) { pref2[lane * 8 + j] = run; run += c[j]; }
        if (lane == 63) stot2 = incl;
    }
    __syncthreads();

    // walk2: thread = atom; emit compacted 8B {d, fc|spc}
    if (tid < NATOM) {
        const int a  = tid;
        const int j0 = (int)pref[a];
        const int j1 = min(j0 + (int)lcnt[a], BLKCAP4);
        unsigned w = pref2[a];
        for (int j = j0; j < j1; ++j) {
            const float4 q = list[j];
            const float d = sqrtf(q.x * q.x + q.y * q.y + q.z * q.z + 1e-12f);
            if (d < 5.0f) {
                const float fc = 0.5f * (__cosf(0.62831853071795864769f * d) + 1.f);
                const unsigned fb = (__float_as_uint(fc) & ~7u)
                                  | (__float_as_uint(q.w) & 7u);
                if (w < (unsigned)BLKCAP2)
                    out2[w] = make_float2(d, __uint_as_float(fb));
                ++w;
            }
        }
    }
    __syncthreads();

    const int tot = min((int)stot2, BLKCAP2);  // coalesced sweep (2.3MB total)
    float2* dstr = rec + (size_t)b * BLKCAP2;
    for (int i = tid; i < tot; i += 1024) dstr[i] = out2[i];

    if (tid < NATOM) {
        cnt[((size_t)mol * NATOM + tid) * NSUB + sub] = ccnt[tid];
        soff_g[(size_t)b * NATOM + tid] = pref2[tid];
    }
}

// ---------------------------------------------------------------------------
// K2 gather: lean form. 4096 blocks x 256 thr, 4 atoms/block, XCD-swizzled.
// Records arrive compacted {d, fc|spc}: tiny copies (17 x 8B/atom), no
// phase A; tv = sum of 8 tv_part partials; phase B verbatim.
// ---------------------------------------------------------------------------
__global__ __launch_bounds__(256) void gather_kernel(
    const unsigned* __restrict__ cnt, const unsigned* __restrict__ soff_g,
    const float2* __restrict__ rec,
    const float* __restrict__ centers, const float* __restrict__ widths,
    const float* __restrict__ c_emb, const float* __restrict__ tv_part,
    unsigned short* __restrict__ dens_bf, float* __restrict__ tvv)
{
    __shared__ float    cemb[8 * NB];          // 2 KB
    __shared__ float2   list2[ABLK][NSLOT];    // 1.5 KB
    __shared__ unsigned scnt[ABLK][NSUB];
    __shared__ unsigned sofg[ABLK][NSUB];
    __shared__ unsigned soff[ABLK][NSUB];
    __shared__ unsigned mtot[ABLK];

    const int tid   = threadIdx.x;
    const int B     = blockIdx.x;
    const int mol   = B & 31;                  // XCD swizzle
    const int inner = B >> 5;                  // 0..127
    const int a0    = mol * NATOM + inner * ABLK;
    const int ra0   = inner * ABLK;

    for (int i = tid; i < 8 * NB; i += 256) cemb[i] = c_emb[i];
    if (tid < ABLK * NSUB) {                   // 32 loads
        const int al = tid >> 3, s = tid & 7;
        scnt[al][s] = cnt[(size_t)(a0 + al) * NSUB + s];
        sofg[al][s] = soff_g[(size_t)(s * NMOL + mol) * NATOM + (ra0 + al)];
    }
    __syncthreads();

    if (tid < ABLK) {                          // per-atom prefix + zero-pad
        int o = 0;
#pragma unroll
        for (int s = 0; s < NSUB; ++s) {
            soff[tid][s] = (unsigned)o;
            o += min((int)scnt[tid][s], NSLOT - o);
        }
        const int mp = (o + 7) & ~7;           // pad to multiple of 8
        mtot[tid] = (unsigned)(mp <= NSLOT ? mp : NSLOT & ~7);
        for (int k = o; k < mp && k < NSLOT; ++k)
            list2[tid][k] = make_float2(0.f, 0.f);
    }
    __syncthreads();

    {   // segment copy: 8 threads per (atom, sub) segment (32 segments)
        const int seg = tid >> 3;              // 0..31
        const int prt = tid & 7;
        const int al = seg >> 3, s = seg & 7;
        const int off = (int)soff[al][s];
        const int n = min((int)scnt[al][s], NSLOT - off);
        const float2* src = rec + (size_t)(s * NMOL + mol) * BLKCAP2 + sofg[al][s];
        float2* dst = &list2[al][off];
        for (int k = prt; k < n; k += 8) dst[k] = src[k];
    }
    if (tid < ABLK * 3) {                      // tv: sum the 8 block-partials
        const int al = tid / 3, c = tid - al * 3;
        float s = 0.f;
#pragma unroll
        for (int sb = 0; sb < NSUB; ++sb)
            s += tv_part[((size_t)(sb * NMOL + mol) * NATOM + (ra0 + al)) * 3 + c];
        tvv[(size_t)(a0 + al) * 3 + c] = s;
    }
    __syncthreads();

    const int lane = tid & 63;
    const int al   = tid >> 6;                 // wave = atom
    const int a    = a0 + al;

    const float L2E = 1.4426950408889634f;
    const float wl  = widths[lane];
    const float cl  = centers[lane];
    const float qe  = -wl * L2E;
    const float qb  = 2.f * wl * cl * L2E;
    const float qa  = -wl * cl * cl * L2E;

    // ---- phase B: lane = basis ----
#define REC1(A, dv, fv) { const unsigned f_ = __float_as_uint(fv);           \
        const float v_ = fmaf(dv, fmaf(dv, qe, qb), qa);                     \
        A = fmaf(exp2f(v_) * __uint_as_float(f_ & ~7u),                      \
                 cemb[((f_ & 7u) << 6) | lane], A); }
    const int mp = (int)mtot[al];
    const float4* l4 = reinterpret_cast<const float4*>(list2[al]);
    float acc0 = 0.f, acc1 = 0.f;
    for (int j = 0; j < mp; j += 8) {
        const float4 q0 = l4[(j >> 1) + 0];
        const float4 q1 = l4[(j >> 1) + 1];
        const float4 q2 = l4[(j >> 1) + 2];
        const float4 q3 = l4[(j >> 1) + 3];
        REC1(acc0, q0.x, q0.y) REC1(acc1, q0.z, q0.w)
        REC1(acc0, q1.x, q1.y) REC1(acc1, q1.z, q1.w)
        REC1(acc0, q2.x, q2.y) REC1(acc1, q2.z, q2.w)
        REC1(acc0, q3.x, q3.y) REC1(acc1, q3.z, q3.w)
    }
#undef REC1
    dens_bf[(size_t)a * NB + lane] = f2bf(acc0 + acc1);
}

// ---------------------------------------------------------------------------
// K3 nn via MFMA: verbatim R29 (XCD-swizzled).
// ---------------------------------------------------------------------------
__global__ __launch_bounds__(256) void nn_kernel(
    const unsigned short* __restrict__ dens_bf, const float* __restrict__ tvv,
    const float* __restrict__ W1, const float* __restrict__ b1,
    const float* __restrict__ W2, const float* __restrict__ b2,
    float* __restrict__ dipole)
{
    __shared__ __align__(16) unsigned short w1t[HIDDEN * 72];
    __shared__ float b1_l[HIDDEN], w2_l[HIDDEN];
    __shared__ float sred[4][4][3];

    const int tid   = threadIdx.x;
    const int B     = blockIdx.x;
    const int mol   = B & 31;                  // XCD swizzle
    const int chunk = B >> 5;                  // 0..7

    for (int i = tid; i < NB * HIDDEN; i += 256) {
        const int k = i >> 8, j = i & 255;
        w1t[j * 72 + k] = f2bf(W1[i]);
    }
    if (tid < HIDDEN) { b1_l[tid] = b1[tid]; w2_l[tid] = W2[tid]; }
    __syncthreads();

    const int lane = tid & 63;
    const int wave = tid >> 6;
    const int fr   = lane & 15;
    const int fg   = lane >> 4;
    const int a0w  = mol * NATOM + chunk * 64 + wave * 16;

    bf16x8 afr[2];
#pragma unroll
    for (int kk = 0; kk < 2; ++kk)
        afr[kk] = *reinterpret_cast<const bf16x8*>(
            dens_bf + (size_t)(a0w + fr) * NB + kk * 32 + fg * 8);

    float sdip[4] = {0.f, 0.f, 0.f, 0.f};
#pragma unroll
    for (int nt = 0; nt < 16; ++nt) {
        const bf16x8 bf0 = *reinterpret_cast<const bf16x8*>(
            &w1t[(nt * 16 + fr) * 72 + 0 + fg * 8]);
        const bf16x8 bf1 = *reinterpret_cast<const bf16x8*>(
            &w1t[(nt * 16 + fr) * 72 + 32 + fg * 8]);
        f32x4 acc = {0.f, 0.f, 0.f, 0.f};
        acc = __builtin_amdgcn_mfma_f32_16x16x32_bf16(afr[0], bf0, acc, 0, 0, 0);
        acc = __builtin_amdgcn_mfma_f32_16x16x32_bf16(afr[1], bf1, acc, 0, 0, 0);
        const int j = nt * 16 + fr;
        const float b1v = b1_l[j], w2v = w2_l[j];
#pragma unroll
        for (int i = 0; i < 4; ++i) {
            const float h = acc[i] + b1v;
            sdip[i] += (h / (1.f + __expf(-h))) * w2v;
        }
    }
#pragma unroll
    for (int off = 1; off < 16; off <<= 1) {
#pragma unroll
        for (int i = 0; i < 4; ++i) sdip[i] += __shfl_xor(sdip[i], off);
    }
    if (fr == 0) {
        const float b2v = b2[0];
        float px = 0.f, py = 0.f, pz = 0.f;
#pragma unroll
        for (int i = 0; i < 4; ++i) {
            const int a = a0w + fg * 4 + i;
            const float out = sdip[i] + b2v;
            px += out * tvv[a * 3 + 0];
            py += out * tvv[a * 3 + 1];
            pz += out * tvv[a * 3 + 2];
        }
        sred[wave][fg][0] = px; sred[wave][fg][1] = py; sred[wave][fg][2] = pz;
    }
    __syncthreads();
    if (tid < 3) {
        float s = 0.f;
#pragma unroll
        for (int w = 0; w < 4; ++w)
#pragma unroll
            for (int g = 0; g < 4; ++g) s += sred[w][g][tid];
        unsafeAtomicAdd(&dipole[mol * 3 + tid], s);
    }
}

// ---------------------------------------------------------------------------
extern "C" void kernel_launch(void* const* d_in, const int* in_sizes, int n_in,
                              void* d_out, int out_size, void* d_ws, size_t ws_size,
                              hipStream_t stream)
{
    const float* cart       = (const float*)d_in[0];
    const float* shifts     = (const float*)d_in[1];
    const float* centers    = (const float*)d_in[2];
    const float* widths     = (const float*)d_in[3];
    const float* c_emb      = (const float*)d_in[4];
    const float* W1         = (const float*)d_in[5];
    const float* b1         = (const float*)d_in[6];
    const float* W2         = (const float*)d_in[7];
    const float* b2         = (const float*)d_in[8];
    const int*   species    = (const int*)d_in[10];
    const int*   atom_index = (const int*)d_in[11];

    // ws: cnt(512KB) | soff_g(512KB) | tvv(192KB) | tv_part(1.5MB) |
    //     dens_bf(2MB) | rec(5.8MB)
    unsigned*       cnt     = (unsigned*)d_ws;
    unsigned*       soff_g  = cnt + (size_t)TOTNATOM * NSUB;
    float*          tvv     = (float*)(soff_g + (size_t)NMOL * NSUB * NATOM);
    float*          tv_part = tvv + (size_t)TOTNATOM * 3;
    unsigned short* dens_bf = (unsigned short*)(tv_part + (size_t)NMOL * NSUB * NATOM * 3);
    float2*         rec     = (float2*)(dens_bf + (size_t)TOTNATOM * NB);
    float*          dipole  = (float*)d_out;

    hipLaunchKernelGGL(scatter_kernel, dim3(NMOL * NSUB), dim3(1024), 0, stream,
                       cart, shifts, species, atom_index, cnt, soff_g, rec,
                       tv_part, dipole, out_size);
    hipLaunchKernelGGL(gather_kernel, dim3(TOTNATOM / ABLK), dim3(256), 0, stream,
                       cnt, soff_g, rec, centers, widths, c_emb, tv_part,
                       dens_bf, tvv);
    hipLaunchKernelGGL(nn_kernel, dim3(TOTNATOM / 64), dim3(256), 0, stream,
                       dens_bf, tvv, W1, b1, W2, b2, dipole);
}

// Round 31
// 39.826 us; speedup vs baseline: 5.5765x; 1.0226x over previous
//
#include <hip/hip_runtime.h>

#define NMOL   32
#define NATOM  512
#define NPAIR  32768
#define NB     64
#define HIDDEN 256
#define TOTNATOM (NMOL * NATOM)
#define NSUB   8
#define BLKCAP4 4352   // all-valid records/block (4096 + slack), LDS SoA
#define BLKCAP2 2816   // compacted 8B records/block (global stride)
#define ABLK   4
#define NSLOT  48      // per-atom compacted slots in gather (lambda 17, +7 sigma)

typedef __attribute__((ext_vector_type(8))) short bf16x8;
typedef __attribute__((ext_vector_type(4))) float f32x4;

__device__ __forceinline__ unsigned short f2bf(float x) {   // RNE f32->bf16
    unsigned u = __float_as_uint(x);
    u += 0x7FFFu + ((u >> 16) & 1u);
    return (unsigned short)(u >> 16);
}

// ---------------------------------------------------------------------------
// K1 scatter: R31 slim. (a) list float4 -> SoA 12B (spc packed into lz's 3
// mantissa LSBs, <=2^-21 rel perturbation); (b) out2 staging + sweep DELETED
// -- walk2 emits compacted records directly to global (per-thread contiguous
// runs, block region dense -> line-friendly). LDS 90KB -> 67KB => 2 blocks/CU
// (32 waves) for the latency-bound phase 1.
// ---------------------------------------------------------------------------
__global__ __launch_bounds__(1024) void scatter_kernel(
    const float* __restrict__ cart, const float* __restrict__ shifts,
    const int* __restrict__ species, const int* __restrict__ atom_index,
    unsigned* __restrict__ cnt, unsigned* __restrict__ soff_g,
    float2* __restrict__ rec, float* __restrict__ tv_part,
    float* __restrict__ dipole, int ndip)
{
    __shared__ float    s_cart[NATOM * 3];  // 6 KB
    __shared__ int      s_sp[NATOM];        // 2 KB
    __shared__ unsigned lcnt[NATOM];        // 2 KB (all-valid counts)
    __shared__ unsigned pref[NATOM];        // 2 KB
    __shared__ unsigned ccnt[NATOM];        // 2 KB (in-cutoff counts)
    __shared__ unsigned pref2[NATOM];       // 2 KB
    __shared__ float    lx[BLKCAP4];        // 17 KB
    __shared__ float    ly[BLKCAP4];        // 17 KB
    __shared__ float    lz[BLKCAP4];        // 17 KB (spc in 3 LSBs)

    const int tid  = threadIdx.x;
    const int lane = tid & 63;
    const int wave = tid >> 6;
    const int b    = blockIdx.x;
    const int mol  = b & 31;               // XCD swizzle (R29)
    const int sub  = b >> 5;

    if (b == 0 && tid < ndip) dipole[tid] = 0.f;

    const float* cm = cart + (size_t)mol * NATOM * 3;
    const int*   sp = species + (size_t)mol * NATOM;
    for (int i = tid; i < NATOM * 3; i += 1024) s_cart[i] = cm[i];
    if (tid < NATOM) { lcnt[tid] = 0u; s_sp[tid] = sp[tid]; }
    __syncthreads();

    const int* ai0 = atom_index + (size_t)mol * NPAIR;
    const int* ai1 = ai0 + (size_t)NMOL * NPAIR;
    const float* sh = shifts + (size_t)mol * NPAIR * 3;
    const int base = sub * 4096;

    int   gi0[4], gi1[4];
    float gsx[4], gsy[4], gsz[4];
#pragma unroll
    for (int k = 0; k < 4; ++k) {              // batched global loads
        const int p = base + k * 1024 + tid;
        gi0[k] = ai0[p];
        gi1[k] = ai1[p];
        gsx[k] = sh[p * 3 + 0];
        gsy[k] = sh[p * 3 + 1];
        gsz[k] = sh[p * 3 + 2];
    }

    float    rx[4], ry[4], rz[4];
    unsigned rs[4], rp[4];
    int      ri[4];
#pragma unroll
    for (int k = 0; k < 4; ++k) {
        const int a3 = gi0[k] * 3, b3 = gi1[k] * 3;
        const bool m = (gsx[k] > -1e10f && gsy[k] > -1e10f && gsz[k] > -1e10f);
        ri[k] = -1;
        if (m) {                               // masked pairs contribute nothing
            rx[k] = s_cart[a3 + 0] - s_cart[b3 + 0] + gsx[k];
            ry[k] = s_cart[a3 + 1] - s_cart[b3 + 1] + gsy[k];
            rz[k] = s_cart[a3 + 2] - s_cart[b3 + 2] + gsz[k];
            rs[k] = (unsigned)s_sp[gi1[k]];
            ri[k] = gi0[k];
            rp[k] = atomicAdd(&lcnt[gi0[k]], 1u);   // rtn = within-atom ordinal
        }
    }
    __syncthreads();

    if (wave == 0) {                           // scan lcnt -> pref (exclusive)
        unsigned c[8], s = 0;
#pragma unroll
        for (int j = 0; j < 8; ++j) { c[j] = lcnt[lane * 8 + j]; s += c[j]; }
        unsigned incl = s;
#pragma unroll
        for (int off = 1; off < 64; off <<= 1) {
            const unsigned v = __shfl_up(incl, off);
            if (lane >= off) incl += v;
        }
        unsigned run = incl - s;
#pragma unroll
        for (int j = 0; j < 8; ++j) { pref[lane * 8 + j] = run; run += c[j]; }
    }
    __syncthreads();

#pragma unroll
    for (int k = 0; k < 4; ++k) {              // pass 2: group all-valid (SoA)
        if (ri[k] >= 0) {
            const unsigned idx = pref[ri[k]] + rp[k];
            if (idx < (unsigned)BLKCAP4) {
                lx[idx] = rx[k];
                ly[idx] = ry[k];
                lz[idx] = __uint_as_float((__float_as_uint(rz[k]) & ~7u) | rs[k]);
            }
        }
    }
    __syncthreads();

    // walk1: thread = atom; tv segment-sum + in-cutoff count (atomic-free)
    if (tid < NATOM) {
        const int a  = tid;
        const int j0 = (int)pref[a];
        const int j1 = min(j0 + (int)lcnt[a], BLKCAP4);
        float tx = 0.f, ty = 0.f, tz = 0.f;
        unsigned c2 = 0;
        for (int j = j0; j < j1; ++j) {
            const float x = lx[j], y = ly[j], z = lz[j];
            tx += x; ty += y; tz += z;
            const float d = sqrtf(x * x + y * y + z * z + 1e-12f);
            if (d < 5.0f) ++c2;
        }
        ccnt[a] = c2;
        float* tg = tv_part + ((size_t)b * NATOM + a) * 3;
        tg[0] = tx; tg[1] = ty; tg[2] = tz;
    }
    __syncthreads();

    if (wave == 0) {                           // scan ccnt -> pref2
        unsigned c[8], s = 0;
#pragma unroll
        for (int j = 0; j < 8; ++j) { c[j] = ccnt[lane * 8 + j]; s += c[j]; }
        unsigned incl = s;
#pragma unroll
        for (int off = 1; off < 64; off <<= 1) {
            const unsigned v = __shfl_up(incl, off);
            if (lane >= off) incl += v;
        }
        unsigned run = incl - s;
#pragma unroll
        for (int j = 0; j < 8; ++j) { pref2[lane * 8 + j] = run; run += c[j]; }
    }
    __syncthreads();

    // walk2: thread = atom; emit compacted 8B {d, fc|spc} DIRECT to global
    if (tid < NATOM) {
        const int a  = tid;
        const int j0 = (int)pref[a];
        const int j1 = min(j0 + (int)lcnt[a], BLKCAP4);
        unsigned w = pref2[a];
        float2* dstr = rec + (size_t)b * BLKCAP2;
        for (int j = j0; j < j1; ++j) {
            const float x = lx[j], y = ly[j], z = lz[j];
            const float d = sqrtf(x * x + y * y + z * z + 1e-12f);
            if (d < 5.0f) {
                const float fc = 0.5f * (__cosf(0.62831853071795864769f * d) + 1.f);
                const unsigned fb = (__float_as_uint(fc) & ~7u)
                                  | (__float_as_uint(z) & 7u);
                if (w < (unsigned)BLKCAP2)
                    dstr[w] = make_float2(d, __uint_as_float(fb));
                ++w;
            }
        }
        cnt[((size_t)mol * NATOM + a) * NSUB + sub] = ccnt[a];
        soff_g[(size_t)b * NATOM + a] = pref2[a];
    }
}

// ---------------------------------------------------------------------------
// K2 gather: verbatim R30 (lean: tiny copies + phase B + tv partial sums).
// ---------------------------------------------------------------------------
__global__ __launch_bounds__(256) void gather_kernel(
    const unsigned* __restrict__ cnt, const unsigned* __restrict__ soff_g,
    const float2* __restrict__ rec,
    const float* __restrict__ centers, const float* __restrict__ widths,
    const float* __restrict__ c_emb, const float* __restrict__ tv_part,
    unsigned short* __restrict__ dens_bf, float* __restrict__ tvv)
{
    __shared__ float    cemb[8 * NB];          // 2 KB
    __shared__ float2   list2[ABLK][NSLOT];    // 1.5 KB
    __shared__ unsigned scnt[ABLK][NSUB];
    __shared__ unsigned sofg[ABLK][NSUB];
    __shared__ unsigned soff[ABLK][NSUB];
    __shared__ unsigned mtot[ABLK];

    const int tid   = threadIdx.x;
    const int B     = blockIdx.x;
    const int mol   = B & 31;                  // XCD swizzle
    const int inner = B >> 5;                  // 0..127
    const int a0    = mol * NATOM + inner * ABLK;
    const int ra0   = inner * ABLK;

    for (int i = tid; i < 8 * NB; i += 256) cemb[i] = c_emb[i];
    if (tid < ABLK * NSUB) {                   // 32 loads
        const int al = tid >> 3, s = tid & 7;
        scnt[al][s] = cnt[(size_t)(a0 + al) * NSUB + s];
        sofg[al][s] = soff_g[(size_t)(s * NMOL + mol) * NATOM + (ra0 + al)];
    }
    __syncthreads();

    if (tid < ABLK) {                          // per-atom prefix + zero-pad
        int o = 0;
#pragma unroll
        for (int s = 0; s < NSUB; ++s) {
            soff[tid][s] = (unsigned)o;
            o += min((int)scnt[tid][s], NSLOT - o);
        }
        const int mp = (o + 7) & ~7;           // pad to multiple of 8
        mtot[tid] = (unsigned)(mp <= NSLOT ? mp : NSLOT & ~7);
        for (int k = o; k < mp && k < NSLOT; ++k)
            list2[tid][k] = make_float2(0.f, 0.f);
    }
    __syncthreads();

    {   // segment copy: 8 threads per (atom, sub) segment (32 segments)
        const int seg = tid >> 3;              // 0..31
        const int prt = tid & 7;
        const int al = seg >> 3, s = seg & 7;
        const int off = (int)soff[al][s];
        const int n = min((int)scnt[al][s], NSLOT - off);
        const float2* src = rec + (size_t)(s * NMOL + mol) * BLKCAP2 + sofg[al][s];
        float2* dst = &list2[al][off];
        for (int k = prt; k < n; k += 8) dst[k] = src[k];
    }
    if (tid < ABLK * 3) {                      // tv: sum the 8 block-partials
        const int al = tid / 3, c = tid - al * 3;
        float s = 0.f;
#pragma unroll
        for (int sb = 0; sb < NSUB; ++sb)
            s += tv_part[((size_t)(sb * NMOL + mol) * NATOM + (ra0 + al)) * 3 + c];
        tvv[(size_t)(a0 + al) * 3 + c] = s;
    }
    __syncthreads();

    const int lane = tid & 63;
    const int al   = tid >> 6;                 // wave = atom
    const int a    = a0 + al;

    const float L2E = 1.4426950408889634f;
    const float wl  = widths[lane];
    const float cl  = centers[lane];
    const float qe  = -wl * L2E;
    const float qb  = 2.f * wl * cl * L2E;
    const float qa  = -wl * cl * cl * L2E;

    // ---- phase B: lane = basis ----
#define REC1(A, dv, fv) { const unsigned f_ = __float_as_uint(fv);           \
        const float v_ = fmaf(dv, fmaf(dv, qe, qb), qa);                     \
        A = fmaf(exp2f(v_) * __uint_as_float(f_ & ~7u),                      \
                 cemb[((f_ & 7u) << 6) | lane], A); }
    const int mp = (int)mtot[al];
    const float4* l4 = reinterpret_cast<const float4*>(list2[al]);
    float acc0 = 0.f, acc1 = 0.f;
    for (int j = 0; j < mp; j += 8) {
        const float4 q0 = l4[(j >> 1) + 0];
        const float4 q1 = l4[(j >> 1) + 1];
        const float4 q2 = l4[(j >> 1) + 2];
        const float4 q3 = l4[(j >> 1) + 3];
        REC1(acc0, q0.x, q0.y) REC1(acc1, q0.z, q0.w)
        REC1(acc0, q1.x, q1.y) REC1(acc1, q1.z, q1.w)
        REC1(acc0, q2.x, q2.y) REC1(acc1, q2.z, q2.w)
        REC1(acc0, q3.x, q3.y) REC1(acc1, q3.z, q3.w)
    }
#undef REC1
    dens_bf[(size_t)a * NB + lane] = f2bf(acc0 + acc1);
}

// ---------------------------------------------------------------------------
// K3 nn via MFMA: verbatim R30 (XCD-swizzled).
// ---------------------------------------------------------------------------
__global__ __launch_bounds__(256) void nn_kernel(
    const unsigned short* __restrict__ dens_bf, const float* __restrict__ tvv,
    const float* __restrict__ W1, const float* __restrict__ b1,
    const float* __restrict__ W2, const float* __restrict__ b2,
    float* __restrict__ dipole)
{
    __shared__ __align__(16) unsigned short w1t[HIDDEN * 72];
    __shared__ float b1_l[HIDDEN], w2_l[HIDDEN];
    __shared__ float sred[4][4][3];

    const int tid   = threadIdx.x;
    const int B     = blockIdx.x;
    const int mol   = B & 31;                  // XCD swizzle
    const int chunk = B >> 5;                  // 0..7

    for (int i = tid; i < NB * HIDDEN; i += 256) {
        const int k = i >> 8, j = i & 255;
        w1t[j * 72 + k] = f2bf(W1[i]);
    }
    if (tid < HIDDEN) { b1_l[tid] = b1[tid]; w2_l[tid] = W2[tid]; }
    __syncthreads();

    const int lane = tid & 63;
    const int wave = tid >> 6;
    const int fr   = lane & 15;
    const int fg   = lane >> 4;
    const int a0w  = mol * NATOM + chunk * 64 + wave * 16;

    bf16x8 afr[2];
#pragma unroll
    for (int kk = 0; kk < 2; ++kk)
        afr[kk] = *reinterpret_cast<const bf16x8*>(
            dens_bf + (size_t)(a0w + fr) * NB + kk * 32 + fg * 8);

    float sdip[4] = {0.f, 0.f, 0.f, 0.f};
#pragma unroll
    for (int nt = 0; nt < 16; ++nt) {
        const bf16x8 bf0 = *reinterpret_cast<const bf16x8*>(
            &w1t[(nt * 16 + fr) * 72 + 0 + fg * 8]);
        const bf16x8 bf1 = *reinterpret_cast<const bf16x8*>(
            &w1t[(nt * 16 + fr) * 72 + 32 + fg * 8]);
        f32x4 acc = {0.f, 0.f, 0.f, 0.f};
        acc = __builtin_amdgcn_mfma_f32_16x16x32_bf16(afr[0], bf0, acc, 0, 0, 0);
        acc = __builtin_amdgcn_mfma_f32_16x16x32_bf16(afr[1], bf1, acc, 0, 0, 0);
        const int j = nt * 16 + fr;
        const float b1v = b1_l[j], w2v = w2_l[j];
#pragma unroll
        for (int i = 0; i < 4; ++i) {
            const float h = acc[i] + b1v;
            sdip[i] += (h / (1.f + __expf(-h))) * w2v;
        }
    }
#pragma unroll
    for (int off = 1; off < 16; off <<= 1) {
#pragma unroll
        for (int i = 0; i < 4; ++i) sdip[i] += __shfl_xor(sdip[i], off);
    }
    if (fr == 0) {
        const float b2v = b2[0];
        float px = 0.f, py = 0.f, pz = 0.f;
#pragma unroll
        for (int i = 0; i < 4; ++i) {
            const int a = a0w + fg * 4 + i;
            const float out = sdip[i] + b2v;
            px += out * tvv[a * 3 + 0];
            py += out * tvv[a * 3 + 1];
            pz += out * tvv[a * 3 + 2];
        }
        sred[wave][fg][0] = px; sred[wave][fg][1] = py; sred[wave][fg][2] = pz;
    }
    __syncthreads();
    if (tid < 3) {
        float s = 0.f;
#pragma unroll
        for (int w = 0; w < 4; ++w)
#pragma unroll
            for (int g = 0; g < 4; ++g) s += sred[w][g][tid];
        unsafeAtomicAdd(&dipole[mol * 3 + tid], s);
    }
}

// ---------------------------------------------------------------------------
extern "C" void kernel_launch(void* const* d_in, const int* in_sizes, int n_in,
                              void* d_out, int out_size, void* d_ws, size_t ws_size,
                              hipStream_t stream)
{
    const float* cart       = (const float*)d_in[0];
    const float* shifts     = (const float*)d_in[1];
    const float* centers    = (const float*)d_in[2];
    const float* widths     = (const float*)d_in[3];
    const float* c_emb      = (const float*)d_in[4];
    const float* W1         = (const float*)d_in[5];
    const float* b1         = (const float*)d_in[6];
    const float* W2         = (const float*)d_in[7];
    const float* b2         = (const float*)d_in[8];
    const int*   species    = (const int*)d_in[10];
    const int*   atom_index = (const int*)d_in[11];

    // ws: cnt(512KB) | soff_g(512KB) | tvv(192KB) | tv_part(1.5MB) |
    //     dens_bf(2MB) | rec(5.8MB)
    unsigned*       cnt     = (unsigned*)d_ws;
    unsigned*       soff_g  = cnt + (size_t)TOTNATOM * NSUB;
    float*          tvv     = (float*)(soff_g + (size_t)NMOL * NSUB * NATOM);
    float*          tv_part = tvv + (size_t)TOTNATOM * 3;
    unsigned short* dens_bf = (unsigned short*)(tv_part + (size_t)NMOL * NSUB * NATOM * 3);
    float2*         rec     = (float2*)(dens_bf + (size_t)TOTNATOM * NB);
    float*          dipole  = (float*)d_out;

    hipLaunchKernelGGL(scatter_kernel, dim3(NMOL * NSUB), dim3(1024), 0, stream,
                       cart, shifts, species, atom_index, cnt, soff_g, rec,
                       tv_part, dipole, out_size);
    hipLaunchKernelGGL(gather_kernel, dim3(TOTNATOM / ABLK), dim3(256), 0, stream,
                       cnt, soff_g, rec, centers, widths, c_emb, tv_part,
                       dens_bf, tvv);
    hipLaunchKernelGGL(nn_kernel, dim3(TOTNATOM / 64), dim3(256), 0, stream,
                       dens_bf, tvv, W1, b1, W2, b2, dipole);
}